// Round 1
// baseline (289315.747 us; speedup 1.0000x reference)
//
#include <hip/hip_runtime.h>
#include <math.h>

#define NBLK 256
#define NTHR 512

#define BB    64
#define TIN   512
#define EEE   512
#define TOUTT 800
#define NMEL  80
#define PPP   256
#define ALS   1024
#define DLS   1024
#define ATTD  128
#define KA    1792
#define KD    2560

// ws offsets (in floats)
#define WTA_OFF  0ull          // 4*1024*1792 = 7,340,032
#define WTD_OFF  7340032ull    // 4*1024*2560 = 10,485,760
#define PM_OFF   17825792ull   // 64*512*128  = 4,194,304
#define AH_OFF   22020096ull   // 2*64*1024
#define AC_OFF   22151168ull   // 64*1024
#define DH_OFF   22216704ull   // 2*64*1024
#define DC_OFF   22347776ull   // 64*1024
#define CTX_OFF  22413312ull   // 64*512
#define AW_OFF   22446080ull   // 64*512
#define AWC_OFF  22478848ull   // 64*512
#define EN_OFF   22511616ull   // 64*512
#define XT_OFF   22544384ull   // 2*64*256
#define BAR_OFF  22577152ull   // 1 u32

__device__ __forceinline__ float sigm(float x) { return 1.0f / (1.0f + __expf(-x)); }

__device__ __forceinline__ void gsync(unsigned* bar, unsigned& n) {
  n += 1;
  __syncthreads();
  if (threadIdx.x == 0) {
    __threadfence();
    __hip_atomic_fetch_add(bar, 1u, __ATOMIC_RELAXED, __HIP_MEMORY_SCOPE_AGENT);
    const unsigned tgt = n * (unsigned)NBLK;
    while (__hip_atomic_load(bar, __ATOMIC_RELAXED, __HIP_MEMORY_SCOPE_AGENT) < tgt) {
      __builtin_amdgcn_s_sleep(1);
    }
    __threadfence();
  }
  __syncthreads();
}

// ---- weight transpose: Wt[col][k], col = gate*1024 + cc ----
__global__ void __launch_bounds__(256) transA(const float* __restrict__ Wi,
                                              const float* __restrict__ Wh,
                                              float* __restrict__ Wt) {
  __shared__ float tile[64][65];
  const int tid = threadIdx.x;
  const int kb = (int)blockIdx.x % 28;  // 1792/64
  const int cb = (int)blockIdx.x / 28;  // 4096/64
  const int k0 = kb * 64, c0 = cb * 64;
  for (int i = tid; i < 4096; i += 256) {
    const int r = i >> 6, c = i & 63;
    const int k = k0 + r;
    const float v = (k < 768) ? Wi[(size_t)k * 4096 + c0 + c]
                              : Wh[(size_t)(k - 768) * 4096 + c0 + c];
    tile[c][r] = v;
  }
  __syncthreads();
  for (int i = tid; i < 4096; i += 256) {
    const int c = i >> 6, kk = i & 63;
    Wt[(size_t)(c0 + c) * KA + k0 + kk] = tile[c][kk];
  }
}

__global__ void __launch_bounds__(256) transD(const float* __restrict__ Wi,
                                              const float* __restrict__ Wh,
                                              float* __restrict__ Wt) {
  __shared__ float tile[64][65];
  const int tid = threadIdx.x;
  const int kb = (int)blockIdx.x % 40;  // 2560/64
  const int cb = (int)blockIdx.x / 40;
  const int k0 = kb * 64, c0 = cb * 64;
  for (int i = tid; i < 4096; i += 256) {
    const int r = i >> 6, c = i & 63;
    const int k = k0 + r;
    const float v = (k < 1536) ? Wi[(size_t)k * 4096 + c0 + c]
                               : Wh[(size_t)(k - 1536) * 4096 + c0 + c];
    tile[c][r] = v;
  }
  __syncthreads();
  for (int i = tid; i < 4096; i += 256) {
    const int c = i >> 6, kk = i & 63;
    Wt[(size_t)(c0 + c) * KD + k0 + kk] = tile[c][kk];
  }
}

// ---- pm = enc @ Wm : [B,TIN,ATT] ----
__global__ void __launch_bounds__(128) pmk(const float* __restrict__ enc,
                                           const float* __restrict__ Wm,
                                           float* __restrict__ pm) {
  __shared__ float er[512];
  const int tid = threadIdx.x;
  const int b = (int)blockIdx.x >> 9, tt = (int)blockIdx.x & 511;
  for (int i = tid; i < 512; i += 128) er[i] = enc[((size_t)b * TIN + tt) * EEE + i];
  __syncthreads();
  float s = 0.f;
  #pragma unroll 4
  for (int k = 0; k < 512; ++k) s += er[k] * Wm[k * ATTD + tid];
  pm[((size_t)b * TIN + tt) * ATTD + tid] = s;
}

// one GEMM segment: 4 gate-dots over contiguous virtual-k range
__device__ __forceinline__ void gemm_seg(const float* src, int b, int stride, int vk0, int len,
                                         const float* w0, const float* w1,
                                         const float* w2, const float* w3,
                                         float& a0, float& a1, float& a2, float& a3) {
  const float* s = src + (size_t)b * stride;
  #pragma unroll 4
  for (int k = 0; k < len; k += 4) {
    const float4 xv = *reinterpret_cast<const float4*>(s + k);
    const int vk = vk0 + k;
    const float4 wi = *reinterpret_cast<const float4*>(w0 + vk);
    const float4 wf = *reinterpret_cast<const float4*>(w1 + vk);
    const float4 wg = *reinterpret_cast<const float4*>(w2 + vk);
    const float4 wo = *reinterpret_cast<const float4*>(w3 + vk);
    a0 += xv.x * wi.x + xv.y * wi.y + xv.z * wi.z + xv.w * wi.w;
    a1 += xv.x * wf.x + xv.y * wf.y + xv.z * wf.z + xv.w * wf.w;
    a2 += xv.x * wg.x + xv.y * wg.y + xv.z * wg.z + xv.w * wg.w;
    a3 += xv.x * wo.x + xv.y * wo.y + xv.z * wo.z + xv.w * wo.w;
  }
}

__device__ __forceinline__ void mel_gate(int b, int tcol, const float* dhb, const float* ctxp,
                                         const float* Wproj, const float* bproj,
                                         const float* Wgate, const float* bgate,
                                         float* out_mel, float* out_gate, float* melp) {
  const int tid = threadIdx.x;
  const int m = tid & 127, ks = tid >> 7;
  if (m <= 80) {
    const float* dr = dhb + (size_t)b * DLS;
    const float* cr = ctxp + (size_t)b * EEE;
    float s = 0.f;
    const int k0 = ks * 384;
    for (int k = k0; k < k0 + 384; ++k) {
      const float x = (k < DLS) ? dr[k] : cr[k - DLS];
      s += x * ((m < NMEL) ? Wproj[k * NMEL + m] : Wgate[k]);
    }
    melp[ks * 81 + m] = s;
  }
  __syncthreads();
  if (tid <= 80) {
    const float s = melp[tid] + melp[81 + tid] + melp[162 + tid] + melp[243 + tid];
    if (tid < NMEL) out_mel[(size_t)b * NMEL * TOUTT + (size_t)tid * TOUTT + tcol] = s + bproj[tid];
    else            out_gate[(size_t)b * TOUTT + tcol] = s + bgate[0];
  }
}

__global__ void __launch_bounds__(NTHR)
decoder_loop(const float* __restrict__ enc, const float* __restrict__ dec_in,
             const int* __restrict__ tlen,
             const float* __restrict__ Wp1, const float* __restrict__ Wp2,
             const float* __restrict__ b_a, const float* __restrict__ Wq,
             const float* __restrict__ Wv, const float* __restrict__ Kloc,
             const float* __restrict__ Wloc, const float* __restrict__ b_d,
             const float* __restrict__ Wproj, const float* __restrict__ bproj,
             const float* __restrict__ Wgate, const float* __restrict__ bgate,
             const float* __restrict__ Wta, const float* __restrict__ Wtd,
             const float* __restrict__ pm,
             float* __restrict__ ah, float* __restrict__ ac,
             float* __restrict__ dh, float* __restrict__ dc,
             float* __restrict__ ctx, float* __restrict__ aw,
             float* __restrict__ awc, float* __restrict__ energ,
             float* __restrict__ xtb, unsigned* bar,
             float* __restrict__ out_mel, float* __restrict__ out_gate,
             float* __restrict__ out_align) {
  __shared__ float smem[6400];
  const int tid = threadIdx.x;
  const int bid = (int)blockIdx.x;
  unsigned syncn = 0;

  // prologue: zero state
  {
    const int gid = bid * NTHR + tid;
    if (gid < BB * ALS) { ah[gid] = 0.f; ac[gid] = 0.f; dh[gid] = 0.f; dc[gid] = 0.f; }
    if (gid < BB * EEE) { ctx[gid] = 0.f; aw[gid] = 0.f; awc[gid] = 0.f; }
    if (gid < BB * PPP) xtb[gid] = 0.f;
  }
  gsync(bar, syncn);

  for (int t = 0; t < TOUTT; ++t) {
    // ---------- P1: attention LSTM (gates + cell) ----------
    {
      const int b = tid & 63;
      const int q = (tid >> 6) & 3;
      const int kh = tid >> 8;
      const int cc = __builtin_amdgcn_readfirstlane(bid * 4 + q);
      const float* ah_r = ah + (size_t)(t & 1) * BB * ALS;
      const float* xsrc = xtb + (size_t)(t & 1) * BB * PPP;
      const float* w0 = Wta + (size_t)(cc) * KA;
      const float* w1 = Wta + (size_t)(1024 + cc) * KA;
      const float* w2 = Wta + (size_t)(2048 + cc) * KA;
      const float* w3 = Wta + (size_t)(3072 + cc) * KA;
      float a0, a1, a2, a3;
      if (kh == 0) { a0 = b_a[cc]; a1 = b_a[1024 + cc]; a2 = b_a[2048 + cc]; a3 = b_a[3072 + cc]; }
      else { a0 = a1 = a2 = a3 = 0.f; }
      if (kh == 0) {
        gemm_seg(xsrc, b, PPP, 0, 256, w0, w1, w2, w3, a0, a1, a2, a3);
        gemm_seg(ctx,  b, EEE, 256, 512, w0, w1, w2, w3, a0, a1, a2, a3);
        gemm_seg(ah_r, b, ALS, 768, 128, w0, w1, w2, w3, a0, a1, a2, a3);
      } else {
        gemm_seg(ah_r + 128, b, ALS, 896, 896, w0, w1, w2, w3, a0, a1, a2, a3);
      }
      float* psh = smem;
      if (kh == 1) {
        const int l = tid & 255;
        psh[l] = a0; psh[256 + l] = a1; psh[512 + l] = a2; psh[768 + l] = a3;
      }
      __syncthreads();
      if (kh == 0) {
        a0 += psh[tid]; a1 += psh[256 + tid]; a2 += psh[512 + tid]; a3 += psh[768 + tid];
        const int idx = b * ALS + cc;
        const float ig = sigm(a0), fg = sigm(a1), gg = tanhf(a2), og = sigm(a3);
        const float cn = fg * ac[idx] + ig * gg;
        ac[idx] = cn;
        ah[(size_t)((t + 1) & 1) * BB * ALS + idx] = og * tanhf(cn);
      }
    }
    gsync(bar, syncn);

    // ---------- P2a: q + location conv + energies (+ mel/gate of t-1) ----------
    {
      const int b = bid >> 2;
      const int chn = bid & 3;
      const int tts = chn * 128;
      float* awl  = smem;          // 544
      float* awcl = smem + 544;    // 544
      float* locl = smem + 1088;   // 128*33 = 4224
      float* ql   = smem + 5312;   // 136
      float* qp   = smem + 5448;   // 512
      float* melp = smem + 5960;   // 324
      for (int i = tid; i < 542; i += NTHR) {
        const bool inb = (i >= 15) && (i < 527);
        awl[i]  = inb ? aw[b * TIN + i - 15] : 0.f;
        awcl[i] = inb ? awc[b * TIN + i - 15] : 0.f;
      }
      {
        const int a = tid & 127, kq = tid >> 7;
        const float* ahn = ah + (size_t)((t + 1) & 1) * BB * ALS + (size_t)b * ALS + kq * 256;
        float s = 0.f;
        #pragma unroll 4
        for (int k = 0; k < 256; ++k) s += ahn[k] * Wq[(kq * 256 + k) * ATTD + a];
        qp[kq * 128 + a] = s;
      }
      __syncthreads();
      if (tid < 128) {
        const int a = tid;
        ql[a + (a >> 5)] = qp[a] + qp[128 + a] + qp[256 + a] + qp[384 + a];
      }
      #pragma unroll
      for (int s8 = 0; s8 < 8; ++s8) {
        const int idx = tid + s8 * NTHR;
        const int f = idx & 31, ttl = idx >> 5;
        const float* k0p = Kloc + f * 62;
        const float* k1p = k0p + 31;
        float acc = 0.f;
        #pragma unroll
        for (int k = 0; k < 31; ++k)
          acc += awl[tts + ttl + k] * k0p[k] + awcl[tts + ttl + k] * k1p[k];
        locl[ttl * 33 + f] = acc;
      }
      __syncthreads();
      {
        const int aq = tid & 3, ttl = tid >> 2;
        const int tt = tts + ttl;
        float lf[32];
        #pragma unroll
        for (int f = 0; f < 32; ++f) lf[f] = locl[ttl * 33 + f];
        const float* pmrow = pm + (size_t)(b * TIN + tt) * ATTD;
        float e = 0.f;
        for (int i = 0; i < 32; ++i) {
          const int a = aq * 32 + i;
          float pl = 0.f;
          #pragma unroll
          for (int f = 0; f < 32; ++f) pl += lf[f] * Wloc[f * ATTD + a];
          e += Wv[a] * tanhf(ql[a + (a >> 5)] + pl + pmrow[a]);
        }
        e += __shfl_xor(e, 1);
        e += __shfl_xor(e, 2);
        if (aq == 0) energ[b * TIN + tt] = e;
      }
      if (chn == 0 && t > 0)
        mel_gate(b, t - 1, dh + (size_t)(t & 1) * BB * DLS, ctx,
                 Wproj, bproj, Wgate, bgate, out_mel, out_gate, melp);
    }
    gsync(bar, syncn);

    // ---------- P2b: softmax + context (blocks 0..63); prenet t+1 (64..127) ----------
    if (bid < 64) {
      const int b = bid;
      const int len = tlen[b];
      float* pl = smem;          // 512
      float* red = smem + 512;   // 16
      const float e = (tid < len) ? energ[b * TIN + tid] : -1e30f;
      float m = e;
      #pragma unroll
      for (int o = 32; o > 0; o >>= 1) m = fmaxf(m, __shfl_xor(m, o));
      if ((tid & 63) == 0) red[tid >> 6] = m;
      __syncthreads();
      if (tid == 0) {
        float mm = red[0];
        #pragma unroll
        for (int i = 1; i < 8; ++i) mm = fmaxf(mm, red[i]);
        red[8] = mm;
      }
      __syncthreads();
      const float M = red[8];
      const float p = (tid < len) ? __expf(e - M) : 0.f;
      float s = p;
      #pragma unroll
      for (int o = 32; o > 0; o >>= 1) s += __shfl_xor(s, o);
      if ((tid & 63) == 0) red[tid >> 6] = s;
      __syncthreads();
      if (tid == 0) {
        float ss = red[0];
        #pragma unroll
        for (int i = 1; i < 8; ++i) ss += red[i];
        red[8] = ss;
      }
      __syncthreads();
      const float an = p * (1.f / red[8]);
      pl[tid] = an;
      aw[b * TIN + tid] = an;
      awc[b * TIN + tid] += an;
      out_align[((size_t)b * TOUTT + t) * TIN + tid] = an;
      __syncthreads();
      {
        const float* er = enc + (size_t)b * TIN * EEE + tid;
        float s2 = 0.f;
        for (int tt = 0; tt < len; ++tt) s2 += pl[tt] * er[(size_t)tt * EEE];
        ctx[b * EEE + tid] = s2;
      }
    } else if (bid < 128) {
      const int b = bid - 64;
      float* xl = smem;          // 80
      float* h1l = smem + 96;    // 256
      if (tid < NMEL) xl[tid] = dec_in[(size_t)b * NMEL * TOUTT + (size_t)tid * TOUTT + t];
      __syncthreads();
      if (tid < PPP) {
        float s = 0.f;
        #pragma unroll 4
        for (int k = 0; k < NMEL; ++k) s += xl[k] * Wp1[k * PPP + tid];
        h1l[tid] = fmaxf(s, 0.f);
      }
      __syncthreads();
      if (tid < PPP) {
        float s = 0.f;
        #pragma unroll 4
        for (int k = 0; k < PPP; ++k) s += h1l[k] * Wp2[k * PPP + tid];
        xtb[(size_t)((t + 1) & 1) * BB * PPP + b * PPP + tid] = fmaxf(s, 0.f);
      }
    }
    gsync(bar, syncn);

    // ---------- P3: decoder LSTM ----------
    {
      const int b = tid & 63;
      const int q = (tid >> 6) & 3;
      const int kh = tid >> 8;
      const int cc = __builtin_amdgcn_readfirstlane(bid * 4 + q);
      const float* ahn = ah + (size_t)((t + 1) & 1) * BB * ALS;
      const float* dhr = dh + (size_t)(t & 1) * BB * DLS;
      const float* w0 = Wtd + (size_t)(cc) * KD;
      const float* w1 = Wtd + (size_t)(1024 + cc) * KD;
      const float* w2 = Wtd + (size_t)(2048 + cc) * KD;
      const float* w3 = Wtd + (size_t)(3072 + cc) * KD;
      float a0, a1, a2, a3;
      if (kh == 0) { a0 = b_d[cc]; a1 = b_d[1024 + cc]; a2 = b_d[2048 + cc]; a3 = b_d[3072 + cc]; }
      else { a0 = a1 = a2 = a3 = 0.f; }
      if (kh == 0) {
        gemm_seg(ahn, b, ALS, 0, 1024, w0, w1, w2, w3, a0, a1, a2, a3);
        gemm_seg(ctx, b, EEE, 1024, 256, w0, w1, w2, w3, a0, a1, a2, a3);
      } else {
        gemm_seg(ctx + 256, b, EEE, 1280, 256, w0, w1, w2, w3, a0, a1, a2, a3);
        gemm_seg(dhr, b, DLS, 1536, 1024, w0, w1, w2, w3, a0, a1, a2, a3);
      }
      float* psh = smem;
      if (kh == 1) {
        const int l = tid & 255;
        psh[l] = a0; psh[256 + l] = a1; psh[512 + l] = a2; psh[768 + l] = a3;
      }
      __syncthreads();
      if (kh == 0) {
        a0 += psh[tid]; a1 += psh[256 + tid]; a2 += psh[512 + tid]; a3 += psh[768 + tid];
        const int idx = b * DLS + cc;
        const float ig = sigm(a0), fg = sigm(a1), gg = tanhf(a2), og = sigm(a3);
        const float cn = fg * dc[idx] + ig * gg;
        dc[idx] = cn;
        dh[(size_t)((t + 1) & 1) * BB * DLS + idx] = og * tanhf(cn);
      }
    }
    gsync(bar, syncn);
  }

  // epilogue: mel/gate for t = 799
  if ((bid & 3) == 0) {
    float* melp = smem + 5960;
    mel_gate(bid >> 2, TOUTT - 1, dh /* parity 0 */, ctx,
             Wproj, bproj, Wgate, bgate, out_mel, out_gate, melp);
  }
}

extern "C" void kernel_launch(void* const* d_in, const int* in_sizes, int n_in,
                              void* d_out, int out_size, void* d_ws, size_t ws_size,
                              hipStream_t stream) {
  (void)in_sizes; (void)n_in; (void)out_size; (void)ws_size;
  const float* enc    = (const float*)d_in[0];
  const float* dec_in = (const float*)d_in[1];
  const int*   tlen   = (const int*)d_in[2];
  const float* Wp1    = (const float*)d_in[3];
  const float* Wp2    = (const float*)d_in[4];
  const float* Wi_a   = (const float*)d_in[5];
  const float* Wh_a   = (const float*)d_in[6];
  const float* b_a    = (const float*)d_in[7];
  const float* Wq     = (const float*)d_in[8];
  const float* Wm     = (const float*)d_in[9];
  const float* Wv     = (const float*)d_in[10];
  const float* Kloc   = (const float*)d_in[11];
  const float* Wloc   = (const float*)d_in[12];
  const float* Wi_d   = (const float*)d_in[13];
  const float* Wh_d   = (const float*)d_in[14];
  const float* b_d    = (const float*)d_in[15];
  const float* Wproj  = (const float*)d_in[16];
  const float* bproj  = (const float*)d_in[17];
  const float* Wgate  = (const float*)d_in[18];
  const float* bgate  = (const float*)d_in[19];

  float* ws = (float*)d_ws;
  float* wta = ws + WTA_OFF;
  float* wtd = ws + WTD_OFF;
  float* pm  = ws + PM_OFF;
  float* ah  = ws + AH_OFF;
  float* ac  = ws + AC_OFF;
  float* dh  = ws + DH_OFF;
  float* dc  = ws + DC_OFF;
  float* ctx = ws + CTX_OFF;
  float* aw  = ws + AW_OFF;
  float* awc = ws + AWC_OFF;
  float* en  = ws + EN_OFF;
  float* xtb = ws + XT_OFF;
  unsigned* bar = (unsigned*)(ws + BAR_OFF);

  float* out_mel   = (float*)d_out;
  float* out_gate  = out_mel + (size_t)BB * NMEL * TOUTT;          // 4,096,000
  float* out_align = out_gate + (size_t)BB * TOUTT;                // +51,200

  hipMemsetAsync(bar, 0, sizeof(unsigned), stream);
  transA<<<dim3(28 * 64), dim3(256), 0, stream>>>(Wi_a, Wh_a, wta);
  transD<<<dim3(40 * 64), dim3(256), 0, stream>>>(Wi_d, Wh_d, wtd);
  pmk<<<dim3(BB * TIN), dim3(128), 0, stream>>>(enc, Wm, pm);
  decoder_loop<<<dim3(NBLK), dim3(NTHR), 0, stream>>>(
      enc, dec_in, tlen, Wp1, Wp2, b_a, Wq, Wv, Kloc, Wloc, b_d,
      Wproj, bproj, Wgate, bgate, wta, wtd, pm,
      ah, ac, dh, dc, ctx, aw, awc, en, xtb, bar,
      out_mel, out_gate, out_align);
}

// Round 2
// 226063.330 us; speedup vs baseline: 1.2798x; 1.2798x over previous
//
#include <hip/hip_runtime.h>
#include <math.h>

#define NBLK 256
#define NTHR 512

#define BB    64
#define TIN   512
#define EEE   512
#define TOUTT 800
#define NMEL  80
#define PPP   256
#define ALS   1024
#define DLS   1024
#define ATTD  128
#define KA    1792
#define KD    2560

typedef _Float16 f16;
typedef f16 f16x8 __attribute__((ext_vector_type(8)));
typedef float f32x4 __attribute__((ext_vector_type(4)));

// ---- ws carve (float units) ----
#define WTA_OFF   0ull          // f16[4096*1792] -> 3,670,016 floats
#define WTD_OFF   3670016ull    // f16[4096*2560] -> 5,242,880 floats
#define PM_OFF    8912896ull    // f32[64*512*128] = 4,194,304
#define XA_OFF    13107200ull   // f16[2*64*1792] -> 114,688 floats
#define XD_OFF    13221888ull   // f16[2*64*2560] -> 163,840 floats
#define AHF_OFF   13385728ull   // f32[64*1024]
#define DHF_OFF   13451264ull
#define AC_OFF    13516800ull
#define DC_OFF    13582336ull
#define CTXF_OFF  13647872ull   // f32[2*64*512]
#define AW_OFF    13713408ull   // f32[64*512]
#define AWC_OFF   13746176ull
#define EN_OFF    13778944ull
#define BAR_OFF   13811712ull

__device__ __forceinline__ float sigm(float x) { return 1.0f / (1.0f + __expf(-x)); }

__device__ __forceinline__ void gsync(unsigned* bar, unsigned& n) {
  n += 1;
  __syncthreads();
  if (threadIdx.x == 0) {
    __threadfence();
    __hip_atomic_fetch_add(bar, 1u, __ATOMIC_RELAXED, __HIP_MEMORY_SCOPE_AGENT);
    const unsigned tgt = n * (unsigned)NBLK;
    while (__hip_atomic_load(bar, __ATOMIC_RELAXED, __HIP_MEMORY_SCOPE_AGENT) < tgt) {
      __builtin_amdgcn_s_sleep(1);
    }
    __threadfence();
  }
  __syncthreads();
}

// ---- weight transpose + f16 convert: Wt[col][k] ----
__global__ void __launch_bounds__(256) transA(const float* __restrict__ Wi,
                                              const float* __restrict__ Wh,
                                              f16* __restrict__ Wt) {
  __shared__ float tile[64][65];
  const int tid = threadIdx.x;
  const int kb = (int)blockIdx.x % 28;
  const int cb = (int)blockIdx.x / 28;
  const int k0 = kb * 64, c0 = cb * 64;
  for (int i = tid; i < 4096; i += 256) {
    const int r = i >> 6, c = i & 63;
    const int k = k0 + r;
    const float v = (k < 768) ? Wi[(size_t)k * 4096 + c0 + c]
                              : Wh[(size_t)(k - 768) * 4096 + c0 + c];
    tile[c][r] = v;
  }
  __syncthreads();
  for (int i = tid; i < 4096; i += 256) {
    const int c = i >> 6, kk = i & 63;
    Wt[(size_t)(c0 + c) * KA + k0 + kk] = (f16)tile[c][kk];
  }
}

__global__ void __launch_bounds__(256) transD(const float* __restrict__ Wi,
                                              const float* __restrict__ Wh,
                                              f16* __restrict__ Wt) {
  __shared__ float tile[64][65];
  const int tid = threadIdx.x;
  const int kb = (int)blockIdx.x % 40;
  const int cb = (int)blockIdx.x / 40;
  const int k0 = kb * 64, c0 = cb * 64;
  for (int i = tid; i < 4096; i += 256) {
    const int r = i >> 6, c = i & 63;
    const int k = k0 + r;
    const float v = (k < 1536) ? Wi[(size_t)k * 4096 + c0 + c]
                               : Wh[(size_t)(k - 1536) * 4096 + c0 + c];
    tile[c][r] = v;
  }
  __syncthreads();
  for (int i = tid; i < 4096; i += 256) {
    const int c = i >> 6, kk = i & 63;
    Wt[(size_t)(c0 + c) * KD + k0 + kk] = (f16)tile[c][kk];
  }
}

// ---- pm = enc @ Wm (fp32) ----
__global__ void __launch_bounds__(128) pmk(const float* __restrict__ enc,
                                           const float* __restrict__ Wm,
                                           float* __restrict__ pm) {
  __shared__ float er[512];
  const int tid = threadIdx.x;
  const int b = (int)blockIdx.x >> 9, tt = (int)blockIdx.x & 511;
  for (int i = tid; i < 512; i += 128) er[i] = enc[((size_t)b * TIN + tt) * EEE + i];
  __syncthreads();
  float s = 0.f;
  #pragma unroll 4
  for (int k = 0; k < 512; ++k) s += er[k] * Wm[k * ATTD + tid];
  pm[((size_t)b * TIN + tt) * ATTD + tid] = s;
}

__device__ __forceinline__ void mel_gate(int b, int tcol, const float* dhb, const float* ctxp,
                                         const float* Wproj, const float* bproj,
                                         const float* Wgate, const float* bgate,
                                         float* out_mel, float* out_gate, float* melp) {
  const int tid = threadIdx.x;
  const int m = tid & 127, ks = tid >> 7;
  if (m <= 80) {
    const float* dr = dhb + (size_t)b * DLS;
    const float* cr = ctxp + (size_t)b * EEE;
    float s = 0.f;
    const int k0 = ks * 384;
    for (int k = k0; k < k0 + 384; ++k) {
      const float x = (k < DLS) ? dr[k] : cr[k - DLS];
      s += x * ((m < NMEL) ? Wproj[k * NMEL + m] : Wgate[k]);
    }
    melp[ks * 81 + m] = s;
  }
  __syncthreads();
  if (tid <= 80) {
    const float s = melp[tid] + melp[81 + tid] + melp[162 + tid] + melp[243 + tid];
    if (tid < NMEL) out_mel[(size_t)b * NMEL * TOUTT + (size_t)tid * TOUTT + tcol] = s + bproj[tid];
    else            out_gate[(size_t)b * TOUTT + tcol] = s + bgate[0];
  }
}

__global__ void __launch_bounds__(NTHR, 1)
decoder_loop(const float* __restrict__ enc, const float* __restrict__ dec_in,
             const int* __restrict__ tlen,
             const float* __restrict__ Wp1, const float* __restrict__ Wp2,
             const float* __restrict__ b_a, const float* __restrict__ Wq,
             const float* __restrict__ Wv, const float* __restrict__ Kloc,
             const float* __restrict__ Wloc, const float* __restrict__ b_d,
             const float* __restrict__ Wproj, const float* __restrict__ bproj,
             const float* __restrict__ Wgate, const float* __restrict__ bgate,
             const f16* __restrict__ wta_h, const f16* __restrict__ wtd_h,
             const float* __restrict__ pm,
             f16* __restrict__ xa_h, f16* __restrict__ xd_h,
             float* __restrict__ ahf, float* __restrict__ dhf,
             float* __restrict__ ac, float* __restrict__ dc,
             float* __restrict__ ctxf,
             float* __restrict__ aw, float* __restrict__ awc,
             float* __restrict__ energ, unsigned* bar,
             float* __restrict__ out_mel, float* __restrict__ out_gate,
             float* __restrict__ out_align) {
  __shared__ f16 wfA[28672];   // 56 ks * 64 lanes * 8  (57,344 B)
  __shared__ f16 wfD[40960];   // 80 ks * 64 lanes * 8  (81,920 B)
  __shared__ float smem[5960]; // 23,840 B  (total LDS 163,104 <= 163,840)

  const int tid = threadIdx.x;
  const int bid = (int)blockIdx.x;
  const int lane = tid & 63;
  unsigned syncn = 0;

  // ---- prologue: pack B-fragments into LDS (frag order: one ds_read_b128/lane/ks) ----
  for (int i = tid; i < 3584; i += NTHR) {          // P1: 56 ks * 64 lanes
    const int ks = i >> 6, l = i & 63;
    const int n = l & 15, kc = (l >> 4) * 8;
    const int gcol = (n >> 2) * 1024 + bid * 4 + (n & 3);
    const uint4 v = *reinterpret_cast<const uint4*>(wta_h + (size_t)gcol * KA + ks * 32 + kc);
    *reinterpret_cast<uint4*>(&wfA[(size_t)i * 8]) = v;
  }
  for (int i = tid; i < 5120; i += NTHR) {          // P3: 80 ks * 64 lanes
    const int ks = i >> 6, l = i & 63;
    const int n = l & 15, kc = (l >> 4) * 8;
    const int gcol = (n >> 2) * 1024 + bid * 4 + (n & 3);
    const uint4 v = *reinterpret_cast<const uint4*>(wtd_h + (size_t)gcol * KD + ks * 32 + kc);
    *reinterpret_cast<uint4*>(&wfD[(size_t)i * 8]) = v;
  }
  // ---- prologue: zero state ----
  {
    unsigned* za = (unsigned*)xa_h;   // xa+xd contiguous: 278,528 u32
    const int gid = bid * NTHR + tid;
    for (int i = gid; i < 278528; i += NBLK * NTHR) za[i] = 0u;
    float* zf = ahf;                  // ahf..energ contiguous: 425,984 f32
    for (int i = gid; i < 425984; i += NBLK * NTHR) zf[i] = 0.f;
  }
  gsync(bar, syncn);

  for (int t = 0; t < TOUTT; ++t) {
    // ---------- P1: attention LSTM via MFMA ----------
    {
      const int w = tid >> 6;
      const int mt = w & 3, kh = w >> 2;
      const f16* xsrc = xa_h + (size_t)(t & 1) * (BB * KA);
      const f16* arow = xsrc + (size_t)(mt * 16 + (lane & 15)) * KA + kh * 896 + ((lane >> 4) * 8);
      const f16* bbase = wfA + ((size_t)(kh * 28) * 64 + lane) * 8;
      f32x4 c = {0.f, 0.f, 0.f, 0.f};
      #pragma unroll 4
      for (int ks = 0; ks < 28; ++ks) {
        const f16x8 af = *reinterpret_cast<const f16x8*>(arow + ks * 32);
        const f16x8 bf = *reinterpret_cast<const f16x8*>(bbase + (size_t)ks * 512);
        c = __builtin_amdgcn_mfma_f32_16x16x32_f16(af, bf, c, 0, 0, 0);
      }
      float* Call = smem;          // 1024
      float* CallB = smem + 1024;  // 1024
      const int r0 = mt * 16 + (lane >> 4) * 4;
      const int n = lane & 15;
      if (kh == 1) {
        #pragma unroll
        for (int j = 0; j < 4; ++j) CallB[(r0 + j) * 16 + n] = c[j];
      }
      __syncthreads();
      if (kh == 0) {
        #pragma unroll
        for (int j = 0; j < 4; ++j) Call[(r0 + j) * 16 + n] = c[j] + CallB[(r0 + j) * 16 + n];
      }
      __syncthreads();
      if (tid < 256) {
        const int b = tid & 63, q = tid >> 6;
        const int cc = bid * 4 + q;
        const float g0 = Call[b * 16 + q]      + b_a[cc];
        const float g1 = Call[b * 16 + 4 + q]  + b_a[1024 + cc];
        const float g2 = Call[b * 16 + 8 + q]  + b_a[2048 + cc];
        const float g3 = Call[b * 16 + 12 + q] + b_a[3072 + cc];
        const int idx = b * ALS + cc;
        const float cn = sigm(g1) * ac[idx] + sigm(g0) * tanhf(g2);
        ac[idx] = cn;
        const float h = sigm(g3) * tanhf(cn);
        ahf[idx] = h;
        xa_h[(size_t)((t + 1) & 1) * (BB * KA) + (size_t)b * KA + 768 + cc] = (f16)h;
        xd_h[(size_t)(t & 1) * (BB * KD) + (size_t)b * KD + cc] = (f16)h;
      }
    }
    gsync(bar, syncn);

    // ---------- P2a: q + location conv + energies ----------
    {
      const int b = bid >> 2;
      const int chn = bid & 3;
      const int tts = chn * 128;
      float* awl  = smem;          // 544
      float* awcl = smem + 544;    // 544
      float* locl = smem + 1088;   // 128*33 = 4224
      float* ql   = smem + 5312;   // 136
      float* qp   = smem + 5448;   // 512
      for (int i = tid; i < 542; i += NTHR) {
        const bool inb = (i >= 15) && (i < 527);
        awl[i]  = inb ? aw[b * TIN + i - 15] : 0.f;
        awcl[i] = inb ? awc[b * TIN + i - 15] : 0.f;
      }
      {
        const int a = tid & 127, kq = tid >> 7;
        const float* ahn = ahf + (size_t)b * ALS + kq * 256;
        float s = 0.f;
        #pragma unroll 4
        for (int k = 0; k < 256; ++k) s += ahn[k] * Wq[(kq * 256 + k) * ATTD + a];
        qp[kq * 128 + a] = s;
      }
      __syncthreads();
      if (tid < 128) {
        const int a = tid;
        ql[a + (a >> 5)] = qp[a] + qp[128 + a] + qp[256 + a] + qp[384 + a];
      }
      #pragma unroll
      for (int s8 = 0; s8 < 8; ++s8) {
        const int idx = tid + s8 * NTHR;
        const int f = idx & 31, ttl = idx >> 5;
        const float* k0p = Kloc + f * 62;
        const float* k1p = k0p + 31;
        float acc = 0.f;
        #pragma unroll
        for (int k = 0; k < 31; ++k)
          acc += awl[tts + ttl + k] * k0p[k] + awcl[tts + ttl + k] * k1p[k];
        locl[ttl * 33 + f] = acc;
      }
      __syncthreads();
      {
        const int aq = tid & 3, ttl = tid >> 2;
        const int tt = tts + ttl;
        float lf[32];
        #pragma unroll
        for (int f = 0; f < 32; ++f) lf[f] = locl[ttl * 33 + f];
        const float* pmrow = pm + (size_t)(b * TIN + tt) * ATTD;
        float e = 0.f;
        for (int i = 0; i < 32; ++i) {
          const int a = aq * 32 + i;
          float pl = 0.f;
          #pragma unroll
          for (int f = 0; f < 32; ++f) pl += lf[f] * Wloc[f * ATTD + a];
          e += Wv[a] * tanhf(ql[a + (a >> 5)] + pl + pmrow[a]);
        }
        e += __shfl_xor(e, 1);
        e += __shfl_xor(e, 2);
        if (aq == 0) energ[b * TIN + tt] = e;
      }
    }
    gsync(bar, syncn);

    // ---------- P2b: softmax+ctx (0..63) | prenet t+1 (64..127) | mel/gate t-1 (128..191) ----------
    if (bid < 64) {
      const int b = bid;
      const int len = tlen[b];
      float* pl = smem;          // 512
      float* red = smem + 512;   // 16
      float* part = smem + 528;  // 2048
      const float e = (tid < len) ? energ[b * TIN + tid] : -1e30f;
      float m = e;
      #pragma unroll
      for (int o = 32; o > 0; o >>= 1) m = fmaxf(m, __shfl_xor(m, o));
      if ((tid & 63) == 0) red[tid >> 6] = m;
      __syncthreads();
      if (tid == 0) {
        float mm = red[0];
        #pragma unroll
        for (int i = 1; i < 8; ++i) mm = fmaxf(mm, red[i]);
        red[8] = mm;
      }
      __syncthreads();
      const float M = red[8];
      const float p = (tid < len) ? __expf(e - M) : 0.f;
      float s = p;
      #pragma unroll
      for (int o = 32; o > 0; o >>= 1) s += __shfl_xor(s, o);
      if ((tid & 63) == 0) red[tid >> 6] = s;
      __syncthreads();
      if (tid == 0) {
        float ss = red[0];
        #pragma unroll
        for (int i = 1; i < 8; ++i) ss += red[i];
        red[8] = ss;
      }
      __syncthreads();
      const float an = p * (1.f / red[8]);
      pl[tid] = an;
      aw[b * TIN + tid] = an;
      awc[b * TIN + tid] += an;
      out_align[((size_t)b * TOUTT + t) * TIN + tid] = an;
      __syncthreads();
      {
        const int a4 = tid & 127, tq = tid >> 7;
        const float* er = enc + (size_t)b * TIN * EEE + (size_t)a4 * 4;
        float p0 = 0.f, p1 = 0.f, p2 = 0.f, p3 = 0.f;
        #pragma unroll 4
        for (int tt = tq * 128; tt < tq * 128 + 128; ++tt) {
          const float wv = pl[tt];
          const float4 ev = *reinterpret_cast<const float4*>(er + (size_t)tt * EEE);
          p0 += wv * ev.x; p1 += wv * ev.y; p2 += wv * ev.z; p3 += wv * ev.w;
        }
        float4* pp = reinterpret_cast<float4*>(part + tq * 512 + a4 * 4);
        *pp = make_float4(p0, p1, p2, p3);
      }
      __syncthreads();
      {
        const int col = tid;
        const float v = part[col] + part[512 + col] + part[1024 + col] + part[1536 + col];
        ctxf[(size_t)((t + 1) & 1) * (BB * EEE) + b * EEE + col] = v;
        xa_h[(size_t)((t + 1) & 1) * (BB * KA) + (size_t)b * KA + 256 + col] = (f16)v;
        xd_h[(size_t)(t & 1) * (BB * KD) + (size_t)b * KD + 1024 + col] = (f16)v;
      }
    } else if (bid < 128) {
      const int b = bid - 64;
      float* xl = smem;          // 80
      float* h1l = smem + 96;    // 256
      if (tid < NMEL) xl[tid] = dec_in[(size_t)b * NMEL * TOUTT + (size_t)tid * TOUTT + t];
      __syncthreads();
      if (tid < PPP) {
        float s = 0.f;
        #pragma unroll 4
        for (int k = 0; k < NMEL; ++k) s += xl[k] * Wp1[k * PPP + tid];
        h1l[tid] = fmaxf(s, 0.f);
      }
      __syncthreads();
      if (tid < PPP) {
        float s = 0.f;
        #pragma unroll 4
        for (int k = 0; k < PPP; ++k) s += h1l[k] * Wp2[k * PPP + tid];
        xa_h[(size_t)((t + 1) & 1) * (BB * KA) + (size_t)b * KA + tid] = (f16)fmaxf(s, 0.f);
      }
    } else if (bid < 192) {
      if (t > 0)
        mel_gate(bid - 128, t - 1, dhf, ctxf + (size_t)(t & 1) * (BB * EEE),
                 Wproj, bproj, Wgate, bgate, out_mel, out_gate, smem);
    }
    gsync(bar, syncn);

    // ---------- P3: decoder LSTM via MFMA ----------
    {
      const int w = tid >> 6;
      const int mt = w & 3, kh = w >> 2;
      const f16* xsrc = xd_h + (size_t)(t & 1) * (BB * KD);
      const f16* arow = xsrc + (size_t)(mt * 16 + (lane & 15)) * KD + kh * 1280 + ((lane >> 4) * 8);
      const f16* bbase = wfD + ((size_t)(kh * 40) * 64 + lane) * 8;
      f32x4 c = {0.f, 0.f, 0.f, 0.f};
      #pragma unroll 4
      for (int ks = 0; ks < 40; ++ks) {
        const f16x8 af = *reinterpret_cast<const f16x8*>(arow + ks * 32);
        const f16x8 bf = *reinterpret_cast<const f16x8*>(bbase + (size_t)ks * 512);
        c = __builtin_amdgcn_mfma_f32_16x16x32_f16(af, bf, c, 0, 0, 0);
      }
      float* Call = smem;
      float* CallB = smem + 1024;
      const int r0 = mt * 16 + (lane >> 4) * 4;
      const int n = lane & 15;
      if (kh == 1) {
        #pragma unroll
        for (int j = 0; j < 4; ++j) CallB[(r0 + j) * 16 + n] = c[j];
      }
      __syncthreads();
      if (kh == 0) {
        #pragma unroll
        for (int j = 0; j < 4; ++j) Call[(r0 + j) * 16 + n] = c[j] + CallB[(r0 + j) * 16 + n];
      }
      __syncthreads();
      if (tid < 256) {
        const int b = tid & 63, q = tid >> 6;
        const int cc = bid * 4 + q;
        const float g0 = Call[b * 16 + q]      + b_d[cc];
        const float g1 = Call[b * 16 + 4 + q]  + b_d[1024 + cc];
        const float g2 = Call[b * 16 + 8 + q]  + b_d[2048 + cc];
        const float g3 = Call[b * 16 + 12 + q] + b_d[3072 + cc];
        const int idx = b * DLS + cc;
        const float cn = sigm(g1) * dc[idx] + sigm(g0) * tanhf(g2);
        dc[idx] = cn;
        const float h = sigm(g3) * tanhf(cn);
        dhf[idx] = h;
        xd_h[(size_t)((t + 1) & 1) * (BB * KD) + (size_t)b * KD + 1536 + cc] = (f16)h;
      }
    }
    gsync(bar, syncn);
  }

  // epilogue: mel/gate for t = 799 (ctx(799) is in ctxf parity 0)
  if (bid >= 128 && bid < 192) {
    mel_gate(bid - 128, TOUTT - 1, dhf, ctxf,
             Wproj, bproj, Wgate, bgate, out_mel, out_gate, smem);
  }
}

extern "C" void kernel_launch(void* const* d_in, const int* in_sizes, int n_in,
                              void* d_out, int out_size, void* d_ws, size_t ws_size,
                              hipStream_t stream) {
  (void)in_sizes; (void)n_in; (void)out_size; (void)ws_size;
  const float* enc    = (const float*)d_in[0];
  const float* dec_in = (const float*)d_in[1];
  const int*   tlen   = (const int*)d_in[2];
  const float* Wp1    = (const float*)d_in[3];
  const float* Wp2    = (const float*)d_in[4];
  const float* Wi_a   = (const float*)d_in[5];
  const float* Wh_a   = (const float*)d_in[6];
  const float* b_a    = (const float*)d_in[7];
  const float* Wq     = (const float*)d_in[8];
  const float* Wm     = (const float*)d_in[9];
  const float* Wv     = (const float*)d_in[10];
  const float* Kloc   = (const float*)d_in[11];
  const float* Wloc   = (const float*)d_in[12];
  const float* Wi_d   = (const float*)d_in[13];
  const float* Wh_d   = (const float*)d_in[14];
  const float* b_d    = (const float*)d_in[15];
  const float* Wproj  = (const float*)d_in[16];
  const float* bproj  = (const float*)d_in[17];
  const float* Wgate  = (const float*)d_in[18];
  const float* bgate  = (const float*)d_in[19];

  float* ws = (float*)d_ws;
  f16*   wta_h = (f16*)(ws + WTA_OFF);
  f16*   wtd_h = (f16*)(ws + WTD_OFF);
  float* pm    = ws + PM_OFF;
  f16*   xa_h  = (f16*)(ws + XA_OFF);
  f16*   xd_h  = (f16*)(ws + XD_OFF);
  float* ahf   = ws + AHF_OFF;
  float* dhf   = ws + DHF_OFF;
  float* ac    = ws + AC_OFF;
  float* dc    = ws + DC_OFF;
  float* ctxf  = ws + CTXF_OFF;
  float* aw    = ws + AW_OFF;
  float* awc   = ws + AWC_OFF;
  float* en    = ws + EN_OFF;
  unsigned* bar = (unsigned*)(ws + BAR_OFF);

  float* out_mel   = (float*)d_out;
  float* out_gate  = out_mel + (size_t)BB * NMEL * TOUTT;
  float* out_align = out_gate + (size_t)BB * TOUTT;

  hipMemsetAsync(bar, 0, sizeof(unsigned), stream);
  transA<<<dim3(28 * 64), dim3(256), 0, stream>>>(Wi_a, Wh_a, wta_h);
  transD<<<dim3(40 * 64), dim3(256), 0, stream>>>(Wi_d, Wh_d, wtd_h);
  pmk<<<dim3(BB * TIN), dim3(128), 0, stream>>>(enc, Wm, pm);
  decoder_loop<<<dim3(NBLK), dim3(NTHR), 0, stream>>>(
      enc, dec_in, tlen, Wp1, Wp2, b_a, Wq, Wv, Kloc, Wloc, b_d,
      Wproj, bproj, Wgate, bgate, wta_h, wtd_h, pm,
      xa_h, xd_h, ahf, dhf, ac, dc, ctxf, aw, awc, en, bar,
      out_mel, out_gate, out_align);
}

// Round 3
// 191083.752 us; speedup vs baseline: 1.5141x; 1.1831x over previous
//
#include <hip/hip_runtime.h>
#include <math.h>

#define NBLK 256
#define NTHR 512

#define BB    64
#define TIN   512
#define EEE   512
#define TOUTT 800
#define NMEL  80
#define PPP   256
#define ALS   1024
#define DLS   1024
#define ATTD  128
#define KA    1792
#define KD    2560

typedef _Float16 f16;
typedef f16 f16x8 __attribute__((ext_vector_type(8)));
typedef float f32x4 __attribute__((ext_vector_type(4)));

// ---- ws carve (float units) ----
#define WTA_OFF   0ull          // f16[4096*1792]
#define WTD_OFF   3670016ull    // f16[4096*2560]
#define PM_OFF    8912896ull    // f32[64*512*128]
#define PRE_OFF   13107200ull   // f16[800*16384] prenet frags
#define XA_OFF    19660800ull   // f16[2*114688]
#define XD_OFF    19775488ull   // f16[2*163840]
#define AHF_OFF   19939328ull   // f32[64*1024]
#define DHF_OFF   20004864ull
#define AC_OFF    20070400ull
#define DC_OFF    20135936ull
#define CTXF_OFF  20201472ull   // f32[2*64*512]
#define AW_OFF    20267008ull
#define AWC_OFF   20299776ull
#define EN_OFF    20332544ull
#define WQT_OFF   20365312ull   // f16[128*1024]
#define WPJT_OFF  20430848ull   // f16[81*1536]
#define WP1T_OFF  20493056ull   // f16[256*80]
#define WP2T_OFF  20503296ull   // f16[256*256]
#define BAR_OFF   20536064ull   // 272 u32

__device__ __forceinline__ float sigm(float x) { return 1.0f / (1.0f + __expf(-x)); }

// fragment-order address (f16 units) within one parity buffer: A-frag for 16x16x32
__device__ __forceinline__ size_t fragaddr(int b, int k) {
  return (size_t)(k >> 5) * 2048 + (size_t)(b >> 4) * 512 +
         (size_t)(((b & 15) + (((k & 31) >> 3) << 4)) << 3) + (k & 7);
}

// ---- tree grid barrier: 16 arrival counters (64B apart), all blocks poll ----
__device__ __forceinline__ void gsync(unsigned* bar, unsigned& n) {
  n += 1;
  __syncthreads();
  if (threadIdx.x == 0) {
    __threadfence();
    __hip_atomic_fetch_add(&bar[(blockIdx.x & 15) << 4], 1u, __ATOMIC_RELAXED, __HIP_MEMORY_SCOPE_AGENT);
  }
  if (threadIdx.x < 64) {
    const unsigned tgt = n * 16u;
    const unsigned g = (threadIdx.x & 15) << 4;
    while (!__all((threadIdx.x >= 16) ||
                  (__hip_atomic_load(&bar[g], __ATOMIC_RELAXED, __HIP_MEMORY_SCOPE_AGENT) >= tgt)))
      __builtin_amdgcn_s_sleep(1);
    __threadfence();
  }
  __syncthreads();
}

// ---- weight transpose + f16: Wt[col][k] ----
__global__ void __launch_bounds__(256) transA(const float* __restrict__ Wi,
                                              const float* __restrict__ Wh,
                                              f16* __restrict__ Wt) {
  __shared__ float tile[64][65];
  const int tid = threadIdx.x;
  const int kb = (int)blockIdx.x % 28;
  const int cb = (int)blockIdx.x / 28;
  const int k0 = kb * 64, c0 = cb * 64;
  for (int i = tid; i < 4096; i += 256) {
    const int r = i >> 6, c = i & 63;
    const int k = k0 + r;
    const float v = (k < 768) ? Wi[(size_t)k * 4096 + c0 + c]
                              : Wh[(size_t)(k - 768) * 4096 + c0 + c];
    tile[c][r] = v;
  }
  __syncthreads();
  for (int i = tid; i < 4096; i += 256) {
    const int c = i >> 6, kk = i & 63;
    Wt[(size_t)(c0 + c) * KA + k0 + kk] = (f16)tile[c][kk];
  }
}

__global__ void __launch_bounds__(256) transD(const float* __restrict__ Wi,
                                              const float* __restrict__ Wh,
                                              f16* __restrict__ Wt) {
  __shared__ float tile[64][65];
  const int tid = threadIdx.x;
  const int kb = (int)blockIdx.x % 40;
  const int cb = (int)blockIdx.x / 40;
  const int k0 = kb * 64, c0 = cb * 64;
  for (int i = tid; i < 4096; i += 256) {
    const int r = i >> 6, c = i & 63;
    const int k = k0 + r;
    const float v = (k < 1536) ? Wi[(size_t)k * 4096 + c0 + c]
                               : Wh[(size_t)(k - 1536) * 4096 + c0 + c];
    tile[c][r] = v;
  }
  __syncthreads();
  for (int i = tid; i < 4096; i += 256) {
    const int c = i >> 6, kk = i & 63;
    Wt[(size_t)(c0 + c) * KD + k0 + kk] = (f16)tile[c][kk];
  }
}

// ---- pm = enc @ Wm (fp32) ----
__global__ void __launch_bounds__(128) pmk(const float* __restrict__ enc,
                                           const float* __restrict__ Wm,
                                           float* __restrict__ pm) {
  __shared__ float er[512];
  const int tid = threadIdx.x;
  const int b = (int)blockIdx.x >> 9, tt = (int)blockIdx.x & 511;
  for (int i = tid; i < 512; i += 128) er[i] = enc[((size_t)b * TIN + tt) * EEE + i];
  __syncthreads();
  float s = 0.f;
  #pragma unroll 4
  for (int k = 0; k < 512; ++k) s += er[k] * Wm[k * ATTD + tid];
  pm[((size_t)b * TIN + tt) * ATTD + tid] = s;
}

// ---- aux transposes to f16 ----
__global__ void __launch_bounds__(512) transAux(const float* __restrict__ Wq,
                                                const float* __restrict__ Wproj,
                                                const float* __restrict__ Wgate,
                                                const float* __restrict__ Wp1,
                                                const float* __restrict__ Wp2,
                                                f16* __restrict__ wqt,
                                                f16* __restrict__ wpjt,
                                                f16* __restrict__ wp1t,
                                                f16* __restrict__ wp2t) {
  const int idx = (int)blockIdx.x * 512 + (int)threadIdx.x;
  if (idx < 131072) {
    const int a = idx >> 10, k = idx & 1023;
    wqt[idx] = (f16)Wq[k * 128 + a];
  } else if (idx < 131072 + 124416) {
    const int j = idx - 131072;
    const int m = j / 1536, k = j % 1536;
    wpjt[j] = (f16)(m < 80 ? Wproj[k * 80 + m] : Wgate[k]);
  } else if (idx < 131072 + 124416 + 20480) {
    const int j = idx - (131072 + 124416);
    const int col = j / 80, k = j % 80;
    wp1t[j] = (f16)Wp1[k * 256 + col];
  } else if (idx < 131072 + 124416 + 20480 + 65536) {
    const int j = idx - (131072 + 124416 + 20480);
    const int col = j >> 8, k = j & 255;
    wp2t[j] = (f16)Wp2[k * 256 + col];
  }
}

// ---- prenet precompute for all steps -> fragment layout ----
__global__ void __launch_bounds__(512) prenetk(const float* __restrict__ dec_in,
                                               const f16* __restrict__ wp1t,
                                               const f16* __restrict__ wp2t,
                                               f16* __restrict__ pre) {
  __shared__ float xl[64 * 80];
  __shared__ f16 h1l[64 * 264];
  const int t = (int)blockIdx.x;
  const int tid = threadIdx.x;
  f16* out = pre + (size_t)t * 16384;
  if (t == 0) {
    unsigned* o32 = (unsigned*)out;
    for (int i = tid; i < 8192; i += 512) o32[i] = 0u;
    return;
  }
  for (int i = tid; i < 5120; i += 512) {
    const int b = i / 80, m = i % 80;
    xl[b * 80 + m] = dec_in[(size_t)b * (NMEL * TOUTT) + (size_t)m * TOUTT + (t - 1)];
  }
  __syncthreads();
  {
    const int col = tid & 255, bh = tid >> 8;
    for (int bb = 0; bb < 32; ++bb) {
      const int b = bh * 32 + bb;
      float s = 0.f;
      #pragma unroll 4
      for (int k = 0; k < 80; ++k) s += xl[b * 80 + k] * (float)wp1t[col * 80 + k];
      h1l[b * 264 + col] = (f16)fmaxf(s, 0.f);
    }
  }
  __syncthreads();
  {
    const int col = tid & 255, bh = tid >> 8;
    for (int bb = 0; bb < 32; ++bb) {
      const int b = bh * 32 + bb;
      float s = 0.f;
      #pragma unroll 4
      for (int k = 0; k < 256; ++k) s += (float)h1l[b * 264 + k] * (float)wp2t[col * 256 + k];
      out[fragaddr(b, col)] = (f16)fmaxf(s, 0.f);
    }
  }
}

// ---- LSTM epilogue: C-reduce + cell nonlinearity + fragment writes ----
__device__ __forceinline__ void lstm_tail(int bid, int tid, float* smemf,
                                          const f32x4 c, int kh, int mt, int lane,
                                          const float* __restrict__ bias,
                                          float* __restrict__ cstate,
                                          float* __restrict__ hf32,
                                          f16* frag1, int k1off,
                                          f16* frag2, int k2off) {
  float* Call = smemf;
  float* CallB = smemf + 1024;
  const int r0 = mt * 16 + (lane >> 4) * 4;
  const int n = lane & 15;
  if (kh == 1) {
    #pragma unroll
    for (int j = 0; j < 4; ++j) CallB[(r0 + j) * 16 + n] = c[j];
  }
  __syncthreads();
  if (kh == 0) {
    #pragma unroll
    for (int j = 0; j < 4; ++j) Call[(r0 + j) * 16 + n] = c[j] + CallB[(r0 + j) * 16 + n];
  }
  __syncthreads();
  if (tid < 256) {
    const int b = tid & 63, q = tid >> 6;
    const int cc = bid * 4 + q;
    const float g0 = Call[b * 16 + q]      + bias[cc];
    const float g1 = Call[b * 16 + 4 + q]  + bias[1024 + cc];
    const float g2 = Call[b * 16 + 8 + q]  + bias[2048 + cc];
    const float g3 = Call[b * 16 + 12 + q] + bias[3072 + cc];
    const int idx = b * 1024 + cc;
    const float cn = sigm(g1) * cstate[idx] + sigm(g0) * tanhf(g2);
    cstate[idx] = cn;
    const float h = sigm(g3) * tanhf(cn);
    hf32[idx] = h;
    const f16 hh = (f16)h;
    if (frag1) frag1[fragaddr(b, k1off + cc)] = hh;
    if (frag2) frag2[fragaddr(b, k2off + cc)] = hh;
  }
}

// ---- mel/gate projection for (b, half) with transposed f16 weights ----
__device__ __forceinline__ void mel_gate2(int b, int half, int tcol,
                                          const float* __restrict__ dhb,
                                          const float* __restrict__ ctxp,
                                          const f16* __restrict__ wpjt,
                                          const float* __restrict__ bproj,
                                          const float* __restrict__ bgate,
                                          float* __restrict__ out_mel,
                                          float* __restrict__ out_gate,
                                          float* melp) {
  const int tid = threadIdx.x;
  const int nrow = half ? 40 : 41;
  const int ml = tid / 12, kq = tid % 12;
  if (ml < nrow) {
    const int m = half * 41 + ml;
    const f16* wr = wpjt + (size_t)m * 1536 + kq * 128;
    const float* dr = dhb + (size_t)b * DLS;
    const float* cr = ctxp + (size_t)b * EEE;
    float s = 0.f;
    #pragma unroll 4
    for (int k = 0; k < 128; ++k) {
      const int kg = kq * 128 + k;
      const float x = (kg < 1024) ? dr[kg] : cr[kg - 1024];
      s += x * (float)wr[k];
    }
    melp[ml * 12 + kq] = s;
  }
  __syncthreads();
  if (tid < nrow) {
    float s = 0.f;
    #pragma unroll
    for (int j = 0; j < 12; ++j) s += melp[tid * 12 + j];
    const int m = half * 41 + tid;
    if (m < 80) out_mel[(size_t)b * NMEL * TOUTT + (size_t)m * TOUTT + tcol] = s + bproj[m];
    else        out_gate[(size_t)b * TOUTT + tcol] = s + bgate[0];
  }
}

__global__ void __launch_bounds__(NTHR, 1)
decoder_loop(const float* __restrict__ enc, const int* __restrict__ tlen,
             const float* __restrict__ b_a, const float* __restrict__ b_d,
             const float* __restrict__ Wv, const float* __restrict__ Kloc,
             const float* __restrict__ Wloc,
             const float* __restrict__ bproj, const float* __restrict__ bgate,
             const f16* __restrict__ wta_h, const f16* __restrict__ wtd_h,
             const float* __restrict__ pm, const f16* __restrict__ pre_h,
             const f16* __restrict__ wqt, const f16* __restrict__ wpjt,
             f16* __restrict__ xa_h, f16* __restrict__ xd_h,
             float* __restrict__ ahf, float* __restrict__ dhf,
             float* __restrict__ ac, float* __restrict__ dc,
             float* __restrict__ ctxf,
             float* __restrict__ aw, float* __restrict__ awc,
             float* __restrict__ energ, unsigned* bar,
             float* __restrict__ out_mel, float* __restrict__ out_gate,
             float* __restrict__ out_align) {
  __shared__ f16 wfA[28672];   // 57,344 B
  __shared__ f16 wfD[40960];   // 81,920 B
  __shared__ float smem[5960]; // 23,840 B

  const int tid = threadIdx.x;
  const int bid = (int)blockIdx.x;
  const int lane = tid & 63;
  unsigned syncn = 0;

  // ---- prologue: pack B-fragments into LDS ----
  for (int i = tid; i < 3584; i += NTHR) {
    const int ks = i >> 6, l = i & 63;
    const int n = l & 15, kc = (l >> 4) * 8;
    const int gcol = (n >> 2) * 1024 + bid * 4 + (n & 3);
    const uint4 v = *reinterpret_cast<const uint4*>(wta_h + (size_t)gcol * KA + ks * 32 + kc);
    *reinterpret_cast<uint4*>(&wfA[(size_t)i * 8]) = v;
  }
  for (int i = tid; i < 5120; i += NTHR) {
    const int ks = i >> 6, l = i & 63;
    const int n = l & 15, kc = (l >> 4) * 8;
    const int gcol = (n >> 2) * 1024 + bid * 4 + (n & 3);
    const uint4 v = *reinterpret_cast<const uint4*>(wtd_h + (size_t)gcol * KD + ks * 32 + kc);
    *reinterpret_cast<uint4*>(&wfD[(size_t)i * 8]) = v;
  }
  // ---- prologue: zero state ----
  {
    unsigned* za = (unsigned*)xa_h;   // xa+xd contiguous: 278,528 u32
    const int gid = bid * NTHR + tid;
    for (int i = gid; i < 278528; i += NBLK * NTHR) za[i] = 0u;
    float* zf = ahf;                  // ahf..energ contiguous: 425,984 f32
    for (int i = gid; i < 425984; i += NBLK * NTHR) zf[i] = 0.f;
  }
  gsync(bar, syncn);

  const int w = tid >> 6;
  const int mt = w & 3, kh = w >> 2;

  for (int t = 0; t <= TOUTT; ++t) {
    // ================= X: P3(t-1) then P1(t) =================
    if (t > 0) {  // decoder LSTM step t-1
      const f16* xdP = xd_h + (size_t)((t - 1) & 1) * 163840;
      const f16* abase = xdP + (size_t)(kh * 40) * 2048 + mt * 512 + lane * 8;
      const f16* bbase = wfD + ((size_t)(kh * 40) * 64 + lane) * 8;
      f32x4 c = {0.f, 0.f, 0.f, 0.f};
      #pragma unroll 4
      for (int ks = 0; ks < 40; ++ks) {
        const f16x8 af = *reinterpret_cast<const f16x8*>(abase + (size_t)ks * 2048);
        const f16x8 bf = *reinterpret_cast<const f16x8*>(bbase + (size_t)ks * 512);
        c = __builtin_amdgcn_mfma_f32_16x16x32_f16(af, bf, c, 0, 0, 0);
      }
      lstm_tail(bid, tid, smem, c, kh, mt, lane, b_d, dc, dhf,
                xd_h + (size_t)(t & 1) * 163840, 1536, (f16*)0, 0);
    }
    if (t < TOUTT) {  // attention LSTM step t
      const f16* xaP = xa_h + (size_t)(t & 1) * 114688;
      const f16* preP = pre_h + (size_t)t * 16384;
      const f16* bbase = wfA + ((size_t)(kh * 28) * 64 + lane) * 8;
      f32x4 c = {0.f, 0.f, 0.f, 0.f};
      #pragma unroll 4
      for (int ks = 0; ks < 28; ++ks) {
        const int kg = kh * 28 + ks;
        const f16* ap = (kg < 8) ? preP : xaP;
        const f16x8 af = *reinterpret_cast<const f16x8*>(ap + (size_t)kg * 2048 + mt * 512 + lane * 8);
        const f16x8 bf = *reinterpret_cast<const f16x8*>(bbase + (size_t)ks * 512);
        c = __builtin_amdgcn_mfma_f32_16x16x32_f16(af, bf, c, 0, 0, 0);
      }
      lstm_tail(bid, tid, smem, c, kh, mt, lane, b_a, ac, ahf,
                xa_h + (size_t)((t + 1) & 1) * 114688, 768,
                xd_h + (size_t)(t & 1) * 163840, 0);
    }
    gsync(bar, syncn);

    // ================= Y1: energies(t) [all 256] + melgate(t-1) [chn 2,3] =================
    {
      const int b = bid >> 2;
      const int chn = bid & 3;
      if (t < TOUTT) {
        const int tts = chn * 128;
        float* awl  = smem;          // 544
        float* awcl = smem + 544;    // 544
        float* locl = smem + 1088;   // 4224
        float* ql   = smem + 5312;   // 136
        float* qp   = smem + 5448;   // 512
        for (int i = tid; i < 542; i += NTHR) {
          const bool inb = (i >= 15) && (i < 527);
          awl[i]  = inb ? aw[b * TIN + i - 15] : 0.f;
          awcl[i] = inb ? awc[b * TIN + i - 15] : 0.f;
        }
        {
          const int a = tid & 127, kq = tid >> 7;
          const f16* wr = wqt + (size_t)a * 1024 + kq * 256;
          const float* ar = ahf + (size_t)b * ALS + kq * 256;
          float s = 0.f;
          #pragma unroll 4
          for (int k8 = 0; k8 < 32; ++k8) {
            const f16x8 wv = *reinterpret_cast<const f16x8*>(wr + k8 * 8);
            #pragma unroll
            for (int j = 0; j < 8; ++j) s += ar[k8 * 8 + j] * (float)wv[j];
          }
          qp[kq * 128 + a] = s;
        }
        __syncthreads();
        if (tid < 128) {
          const int a = tid;
          ql[a + (a >> 5)] = qp[a] + qp[128 + a] + qp[256 + a] + qp[384 + a];
        }
        #pragma unroll
        for (int s8 = 0; s8 < 8; ++s8) {
          const int idx = tid + s8 * NTHR;
          const int f = idx & 31, ttl = idx >> 5;
          const float* k0p = Kloc + f * 62;
          const float* k1p = k0p + 31;
          float acc = 0.f;
          #pragma unroll
          for (int k = 0; k < 31; ++k)
            acc += awl[tts + ttl + k] * k0p[k] + awcl[tts + ttl + k] * k1p[k];
          locl[ttl * 33 + f] = acc;
        }
        __syncthreads();
        {
          const int aq = tid & 3, ttl = tid >> 2;
          const int tt = tts + ttl;
          float lf[32];
          #pragma unroll
          for (int f = 0; f < 32; ++f) lf[f] = locl[ttl * 33 + f];
          const float* pmrow = pm + (size_t)(b * TIN + tt) * ATTD;
          float e = 0.f;
          for (int i = 0; i < 32; ++i) {
            const int a = aq * 32 + i;
            float pl = 0.f;
            #pragma unroll
            for (int f = 0; f < 32; ++f) pl += lf[f] * Wloc[f * ATTD + a];
            e += Wv[a] * tanhf(ql[a + (a >> 5)] + pl + pmrow[a]);
          }
          e += __shfl_xor(e, 1);
          e += __shfl_xor(e, 2);
          if (aq == 0) energ[b * TIN + tt] = e;
        }
      }
      if (t > 0 && chn >= 2) {
        __syncthreads();
        mel_gate2(b, chn - 2, t - 1, dhf, ctxf + (size_t)((t - 1) & 1) * (BB * EEE),
                  wpjt, bproj, bgate, out_mel, out_gate, smem + 5448);
      }
    }
    if (t == TOUTT) break;
    gsync(bar, syncn);

    // ================= Y2: redundant softmax + ctx e-quarter =================
    {
      const int b = bid >> 2;
      const int eq = bid & 3;
      const int len = tlen[b];
      float* pl  = smem;         // 512
      float* red = smem + 512;   // 16
      float* part = smem + 528;  // 1024
      const float e = (tid < len) ? energ[b * TIN + tid] : -1e30f;
      float m = e;
      #pragma unroll
      for (int o = 32; o > 0; o >>= 1) m = fmaxf(m, __shfl_xor(m, o));
      if ((tid & 63) == 0) red[tid >> 6] = m;
      __syncthreads();
      if (tid == 0) {
        float mm = red[0];
        #pragma unroll
        for (int i = 1; i < 8; ++i) mm = fmaxf(mm, red[i]);
        red[8] = mm;
      }
      __syncthreads();
      const float M = red[8];
      const float p = (tid < len) ? __expf(e - M) : 0.f;
      float s = p;
      #pragma unroll
      for (int o = 32; o > 0; o >>= 1) s += __shfl_xor(s, o);
      if ((tid & 63) == 0) red[tid >> 6] = s;
      __syncthreads();
      if (tid == 0) {
        float ss = red[0];
        #pragma unroll
        for (int i = 1; i < 8; ++i) ss += red[i];
        red[8] = ss;
      }
      __syncthreads();
      const float an = p * (1.f / red[8]);
      pl[tid] = an;
      if (eq == 0) {
        aw[b * TIN + tid] = an;
        awc[b * TIN + tid] += an;
        out_align[((size_t)b * TOUTT + t) * TIN + tid] = an;
      }
      __syncthreads();
      {
        // ctx quarter: e-cols eq*128..+128; wave w handles tt chunk of 64
        const int ww = tid >> 6;
        const float* ebase = enc + (size_t)b * TIN * EEE + eq * 128 + lane * 2;
        float a0 = 0.f, a1 = 0.f;
        #pragma unroll 4
        for (int j = 0; j < 64; ++j) {
          const int tt = ww * 64 + j;
          const float wv = pl[tt];
          const float2 ev = *reinterpret_cast<const float2*>(ebase + (size_t)tt * EEE);
          a0 += wv * ev.x; a1 += wv * ev.y;
        }
        part[ww * 128 + lane * 2]     = a0;
        part[ww * 128 + lane * 2 + 1] = a1;
      }
      __syncthreads();
      if (tid < 128) {
        float v = 0.f;
        #pragma unroll
        for (int ww = 0; ww < 8; ++ww) v += part[ww * 128 + tid];
        const int ecol = eq * 128 + tid;
        ctxf[(size_t)(t & 1) * (BB * EEE) + b * EEE + ecol] = v;
        const f16 hv = (f16)v;
        xa_h[(size_t)((t + 1) & 1) * 114688 + fragaddr(b, 256 + ecol)] = hv;
        xd_h[(size_t)(t & 1) * 163840 + fragaddr(b, 1024 + ecol)] = hv;
      }
    }
    gsync(bar, syncn);
  }
}

extern "C" void kernel_launch(void* const* d_in, const int* in_sizes, int n_in,
                              void* d_out, int out_size, void* d_ws, size_t ws_size,
                              hipStream_t stream) {
  (void)in_sizes; (void)n_in; (void)out_size; (void)ws_size;
  const float* enc    = (const float*)d_in[0];
  const float* dec_in = (const float*)d_in[1];
  const int*   tlen   = (const int*)d_in[2];
  const float* Wp1    = (const float*)d_in[3];
  const float* Wp2    = (const float*)d_in[4];
  const float* Wi_a   = (const float*)d_in[5];
  const float* Wh_a   = (const float*)d_in[6];
  const float* b_a    = (const float*)d_in[7];
  const float* Wq     = (const float*)d_in[8];
  const float* Wm     = (const float*)d_in[9];
  const float* Wv     = (const float*)d_in[10];
  const float* Kloc   = (const float*)d_in[11];
  const float* Wloc   = (const float*)d_in[12];
  const float* Wi_d   = (const float*)d_in[13];
  const float* Wh_d   = (const float*)d_in[14];
  const float* b_d    = (const float*)d_in[15];
  const float* Wproj  = (const float*)d_in[16];
  const float* bproj  = (const float*)d_in[17];
  const float* Wgate  = (const float*)d_in[18];
  const float* bgate  = (const float*)d_in[19];

  float* ws = (float*)d_ws;
  f16*   wta_h = (f16*)(ws + WTA_OFF);
  f16*   wtd_h = (f16*)(ws + WTD_OFF);
  float* pm    = ws + PM_OFF;
  f16*   pre_h = (f16*)(ws + PRE_OFF);
  f16*   xa_h  = (f16*)(ws + XA_OFF);
  f16*   xd_h  = (f16*)(ws + XD_OFF);
  float* ahf   = ws + AHF_OFF;
  float* dhf   = ws + DHF_OFF;
  float* ac    = ws + AC_OFF;
  float* dc    = ws + DC_OFF;
  float* ctxf  = ws + CTXF_OFF;
  float* aw    = ws + AW_OFF;
  float* awc   = ws + AWC_OFF;
  float* en    = ws + EN_OFF;
  f16*   wqt   = (f16*)(ws + WQT_OFF);
  f16*   wpjt  = (f16*)(ws + WPJT_OFF);
  f16*   wp1t  = (f16*)(ws + WP1T_OFF);
  f16*   wp2t  = (f16*)(ws + WP2T_OFF);
  unsigned* bar = (unsigned*)(ws + BAR_OFF);

  float* out_mel   = (float*)d_out;
  float* out_gate  = out_mel + (size_t)BB * NMEL * TOUTT;
  float* out_align = out_gate + (size_t)BB * TOUTT;

  hipMemsetAsync(bar, 0, 272 * sizeof(unsigned), stream);
  transA<<<dim3(28 * 64), dim3(256), 0, stream>>>(Wi_a, Wh_a, wta_h);
  transD<<<dim3(40 * 64), dim3(256), 0, stream>>>(Wi_d, Wh_d, wtd_h);
  pmk<<<dim3(BB * TIN), dim3(128), 0, stream>>>(enc, Wm, pm);
  transAux<<<dim3(667), dim3(512), 0, stream>>>(Wq, Wproj, Wgate, Wp1, Wp2,
                                                wqt, wpjt, wp1t, wp2t);
  prenetk<<<dim3(TOUTT), dim3(512), 0, stream>>>(dec_in, wp1t, wp2t, pre_h);
  decoder_loop<<<dim3(NBLK), dim3(NTHR), 0, stream>>>(
      enc, tlen, b_a, b_d, Wv, Kloc, Wloc, bproj, bgate,
      wta_h, wtd_h, pm, pre_h, wqt, wpjt,
      xa_h, xd_h, ahf, dhf, ac, dc, ctxf, aw, awc, en, bar,
      out_mel, out_gate, out_align);
}

// Round 4
// 77917.908 us; speedup vs baseline: 3.7131x; 2.4524x over previous
//
#include <hip/hip_runtime.h>
#include <math.h>

#define NBLK 256
#define NTHR 512

#define BB    64
#define TIN   512
#define EEE   512
#define TOUTT 800
#define NMEL  80
#define PPP   256
#define ALS   1024
#define DLS   1024
#define ATTD  128
#define KA    1792
#define KD    2560

typedef _Float16 f16;
typedef f16 f16x8 __attribute__((ext_vector_type(8)));
typedef f16 f16x2 __attribute__((ext_vector_type(2)));
typedef float f32x4 __attribute__((ext_vector_type(4)));

// ---- ws carve (float units) ----
#define WTA_OFF   0ull          // f16[4096*1792]
#define WTD_OFF   3670016ull    // f16[4096*2560]
#define PM16_OFF  8912896ull    // f16[64*512*128]
#define ENC16_OFF 11010048ull   // f16[64*512*512]
#define PRE_OFF   19398656ull   // f16[800*16384]
#define XA_OFF    25952256ull   // f16[2*114688]
#define XD_OFF    26066944ull   // f16[2*163840]
#define AHF_OFF   26230784ull   // f32[64*1024]
#define DHF_OFF   26296320ull
#define AC_OFF    26361856ull
#define DC_OFF    26427392ull
#define CTXF_OFF  26492928ull   // f32[2*64*512]
#define WQT_OFF   26558464ull   // f16[128*1024]
#define WPJT_OFF  26624000ull   // f16[81*1536]
#define WP1T_OFF  26686208ull   // f16[256*80]
#define WP2T_OFF  26696448ull   // f16[256*256]
#define WLP_OFF   26729216ull   // u32[128*16]  packed Wloc f16 pairs
#define KLP_OFF   26731264ull   // u32[31*32]   packed Kloc f16 pairs
#define BAR_OFF   26732256ull   // 272 u32

// smem f32 region layout (2048 floats, reused X/Y)
#define PL_O   0     // 512
#define RED_O  512   // 16
#define QL_O   528   // 136
#define PART_O 664   // 1024 (also qp, melp)

__device__ __forceinline__ float sigm(float x) { return 1.0f / (1.0f + __expf(-x)); }
__device__ __forceinline__ float ftanh(float x) {
  const float ex = __expf(2.f * x);
  return (ex - 1.f) / (ex + 1.f);
}

union pk32 { unsigned u; f16x2 h; float f; };
__device__ __forceinline__ unsigned packh2(float a, float b) {
  pk32 p; p.h[0] = (f16)a; p.h[1] = (f16)b; return p.u;
}

// fragment-order address (f16 units): A-frag for 16x16x32
__device__ __forceinline__ size_t fragaddr(int b, int k) {
  return (size_t)(k >> 5) * 2048 + (size_t)(b >> 4) * 512 +
         (size_t)(((b & 15) + (((k & 31) >> 3) << 4)) << 3) + (k & 7);
}

// ---- tree grid barrier ----
__device__ __forceinline__ void gsync(unsigned* bar, unsigned& n) {
  n += 1;
  __syncthreads();
  if (threadIdx.x == 0) {
    __threadfence();
    __hip_atomic_fetch_add(&bar[(blockIdx.x & 15) << 4], 1u, __ATOMIC_RELAXED, __HIP_MEMORY_SCOPE_AGENT);
  }
  if (threadIdx.x < 64) {
    const unsigned tgt = n * 16u;
    const unsigned g = (threadIdx.x & 15) << 4;
    while (!__all((threadIdx.x >= 16) ||
                  (__hip_atomic_load(&bar[g], __ATOMIC_RELAXED, __HIP_MEMORY_SCOPE_AGENT) >= tgt)))
      __builtin_amdgcn_s_sleep(1);
    __threadfence();
  }
  __syncthreads();
}

// ---- weight transpose + f16: Wt[col][k] ----
__global__ void __launch_bounds__(256) transA(const float* __restrict__ Wi,
                                              const float* __restrict__ Wh,
                                              f16* __restrict__ Wt) {
  __shared__ float tile[64][65];
  const int tid = threadIdx.x;
  const int kb = (int)blockIdx.x % 28;
  const int cb = (int)blockIdx.x / 28;
  const int k0 = kb * 64, c0 = cb * 64;
  for (int i = tid; i < 4096; i += 256) {
    const int r = i >> 6, c = i & 63;
    const int k = k0 + r;
    const float v = (k < 768) ? Wi[(size_t)k * 4096 + c0 + c]
                              : Wh[(size_t)(k - 768) * 4096 + c0 + c];
    tile[c][r] = v;
  }
  __syncthreads();
  for (int i = tid; i < 4096; i += 256) {
    const int c = i >> 6, kk = i & 63;
    Wt[(size_t)(c0 + c) * KA + k0 + kk] = (f16)tile[c][kk];
  }
}

__global__ void __launch_bounds__(256) transD(const float* __restrict__ Wi,
                                              const float* __restrict__ Wh,
                                              f16* __restrict__ Wt) {
  __shared__ float tile[64][65];
  const int tid = threadIdx.x;
  const int kb = (int)blockIdx.x % 40;
  const int cb = (int)blockIdx.x / 40;
  const int k0 = kb * 64, c0 = cb * 64;
  for (int i = tid; i < 4096; i += 256) {
    const int r = i >> 6, c = i & 63;
    const int k = k0 + r;
    const float v = (k < 1536) ? Wi[(size_t)k * 4096 + c0 + c]
                               : Wh[(size_t)(k - 1536) * 4096 + c0 + c];
    tile[c][r] = v;
  }
  __syncthreads();
  for (int i = tid; i < 4096; i += 256) {
    const int c = i >> 6, kk = i & 63;
    Wt[(size_t)(c0 + c) * KD + k0 + kk] = (f16)tile[c][kk];
  }
}

// ---- pm = enc @ Wm -> f16 ----
__global__ void __launch_bounds__(128) pmk(const float* __restrict__ enc,
                                           const float* __restrict__ Wm,
                                           f16* __restrict__ pm16) {
  __shared__ float er[512];
  const int tid = threadIdx.x;
  const int b = (int)blockIdx.x >> 9, tt = (int)blockIdx.x & 511;
  for (int i = tid; i < 512; i += 128) er[i] = enc[((size_t)b * TIN + tt) * EEE + i];
  __syncthreads();
  float s = 0.f;
  #pragma unroll 4
  for (int k = 0; k < 512; ++k) s += er[k] * Wm[k * ATTD + tid];
  pm16[((size_t)b * TIN + tt) * ATTD + tid] = (f16)s;
}

// ---- enc -> f16 ----
__global__ void __launch_bounds__(512) enc16k(const float* __restrict__ enc,
                                              f16* __restrict__ e16) {
  const size_t i = ((size_t)blockIdx.x * 512 + threadIdx.x) * 8;
  const float4 v0 = *reinterpret_cast<const float4*>(enc + i);
  const float4 v1 = *reinterpret_cast<const float4*>(enc + i + 4);
  f16x8 o;
  o[0] = (f16)v0.x; o[1] = (f16)v0.y; o[2] = (f16)v0.z; o[3] = (f16)v0.w;
  o[4] = (f16)v1.x; o[5] = (f16)v1.y; o[6] = (f16)v1.z; o[7] = (f16)v1.w;
  *reinterpret_cast<f16x8*>(e16 + i) = o;
}

// ---- aux transposes / packs ----
__global__ void __launch_bounds__(512) transAux(const float* __restrict__ Wq,
                                                const float* __restrict__ Wproj,
                                                const float* __restrict__ Wgate,
                                                const float* __restrict__ Wp1,
                                                const float* __restrict__ Wp2,
                                                const float* __restrict__ Wloc,
                                                const float* __restrict__ Kloc,
                                                f16* __restrict__ wqt,
                                                f16* __restrict__ wpjt,
                                                f16* __restrict__ wp1t,
                                                f16* __restrict__ wp2t,
                                                unsigned* __restrict__ wlocp,
                                                unsigned* __restrict__ klp) {
  const int idx = (int)blockIdx.x * 512 + (int)threadIdx.x;
  if (idx < 131072) {
    const int a = idx >> 10, k = idx & 1023;
    wqt[idx] = (f16)Wq[k * 128 + a];
  } else if (idx < 131072 + 124416) {
    const int j = idx - 131072;
    const int m = j / 1536, k = j % 1536;
    wpjt[j] = (f16)(m < 80 ? Wproj[k * 80 + m] : Wgate[k]);
  } else if (idx < 131072 + 124416 + 20480) {
    const int j = idx - (131072 + 124416);
    const int col = j / 80, k = j % 80;
    wp1t[j] = (f16)Wp1[k * 256 + col];
  } else if (idx < 131072 + 124416 + 20480 + 65536) {
    const int j = idx - (131072 + 124416 + 20480);
    const int col = j >> 8, k = j & 255;
    wp2t[j] = (f16)Wp2[k * 256 + col];
  } else if (idx < 131072 + 124416 + 20480 + 65536 + 2048) {
    const int j = idx - (131072 + 124416 + 20480 + 65536);
    const int a = j >> 4, fp = j & 15;
    wlocp[j] = packh2(Wloc[(2 * fp) * 128 + a], Wloc[(2 * fp + 1) * 128 + a]);
  } else if (idx < 131072 + 124416 + 20480 + 65536 + 2048 + 992) {
    const int j = idx - (131072 + 124416 + 20480 + 65536 + 2048);
    const int k = j >> 5, f = j & 31;
    klp[j] = packh2(Kloc[f * 62 + k], Kloc[f * 62 + 31 + k]);
  }
}

// ---- prenet precompute -> fragment layout ----
__global__ void __launch_bounds__(512) prenetk(const float* __restrict__ dec_in,
                                               const f16* __restrict__ wp1t,
                                               const f16* __restrict__ wp2t,
                                               f16* __restrict__ pre) {
  __shared__ float xl[64 * 80];
  __shared__ f16 h1l[64 * 264];
  const int t = (int)blockIdx.x;
  const int tid = threadIdx.x;
  f16* out = pre + (size_t)t * 16384;
  if (t == 0) {
    unsigned* o32 = (unsigned*)out;
    for (int i = tid; i < 8192; i += 512) o32[i] = 0u;
    return;
  }
  for (int i = tid; i < 5120; i += 512) {
    const int b = i / 80, m = i % 80;
    xl[b * 80 + m] = dec_in[(size_t)b * (NMEL * TOUTT) + (size_t)m * TOUTT + (t - 1)];
  }
  __syncthreads();
  {
    const int col = tid & 255, bh = tid >> 8;
    for (int bb = 0; bb < 32; ++bb) {
      const int b = bh * 32 + bb;
      float s = 0.f;
      #pragma unroll 4
      for (int k = 0; k < 80; ++k) s += xl[b * 80 + k] * (float)wp1t[col * 80 + k];
      h1l[b * 264 + col] = (f16)fmaxf(s, 0.f);
    }
  }
  __syncthreads();
  {
    const int col = tid & 255, bh = tid >> 8;
    for (int bb = 0; bb < 32; ++bb) {
      const int b = bh * 32 + bb;
      float s = 0.f;
      #pragma unroll 4
      for (int k = 0; k < 256; ++k) s += (float)h1l[b * 264 + k] * (float)wp2t[col * 256 + k];
      out[fragaddr(b, col)] = (f16)fmaxf(s, 0.f);
    }
  }
}

// ---- LSTM epilogue ----
__device__ __forceinline__ void lstm_tail(int bid, int tid, float* smemf,
                                          const f32x4 c, int kh, int mt, int lane,
                                          const float* __restrict__ bias,
                                          float* __restrict__ cstate,
                                          float* __restrict__ hf32,
                                          f16* frag1, int k1off,
                                          f16* frag2, int k2off) {
  float* Call = smemf;
  float* CallB = smemf + 1024;
  const int r0 = mt * 16 + (lane >> 4) * 4;
  const int n = lane & 15;
  if (kh == 1) {
    #pragma unroll
    for (int j = 0; j < 4; ++j) CallB[(r0 + j) * 16 + n] = c[j];
  }
  __syncthreads();
  if (kh == 0) {
    #pragma unroll
    for (int j = 0; j < 4; ++j) Call[(r0 + j) * 16 + n] = c[j] + CallB[(r0 + j) * 16 + n];
  }
  __syncthreads();
  if (tid < 256) {
    const int b = tid & 63, q = tid >> 6;
    const int cc = bid * 4 + q;
    const float g0 = Call[b * 16 + q]      + bias[cc];
    const float g1 = Call[b * 16 + 4 + q]  + bias[1024 + cc];
    const float g2 = Call[b * 16 + 8 + q]  + bias[2048 + cc];
    const float g3 = Call[b * 16 + 12 + q] + bias[3072 + cc];
    const int idx = b * 1024 + cc;
    const float cn = sigm(g1) * cstate[idx] + sigm(g0) * ftanh(g2);
    cstate[idx] = cn;
    const float h = sigm(g3) * ftanh(cn);
    hf32[idx] = h;
    const f16 hh = (f16)h;
    if (frag1) frag1[fragaddr(b, k1off + cc)] = hh;
    if (frag2) frag2[fragaddr(b, k2off + cc)] = hh;
  }
}

// ---- mel/gate projection ----
__device__ __forceinline__ void mel_gate2(int b, int half, int tcol,
                                          const float* __restrict__ dhb,
                                          const float* __restrict__ ctxp,
                                          const f16* __restrict__ wpjt,
                                          const float* __restrict__ bproj,
                                          const float* __restrict__ bgate,
                                          float* __restrict__ out_mel,
                                          float* __restrict__ out_gate,
                                          float* melp) {
  const int tid = threadIdx.x;
  const int nrow = half ? 40 : 41;
  const int ml = tid / 12, kq = tid % 12;
  if (ml < nrow) {
    const int m = half * 41 + ml;
    const f16* wr = wpjt + (size_t)m * 1536 + kq * 128;
    const float* dr = dhb + (size_t)b * DLS;
    const float* cr = ctxp + (size_t)b * EEE;
    float s = 0.f;
    #pragma unroll
    for (int k8 = 0; k8 < 16; ++k8) {
      const f16x8 wv = *reinterpret_cast<const f16x8*>(wr + k8 * 8);
      #pragma unroll
      for (int j = 0; j < 8; ++j) {
        const int kg = kq * 128 + k8 * 8 + j;
        const float x = (kg < 1024) ? dr[kg] : cr[kg - 1024];
        s += x * (float)wv[j];
      }
    }
    melp[ml * 12 + kq] = s;
  }
  __syncthreads();
  if (tid < nrow) {
    float s = 0.f;
    #pragma unroll
    for (int j = 0; j < 12; ++j) s += melp[tid * 12 + j];
    const int m = half * 41 + tid;
    if (m < 80) out_mel[(size_t)b * NMEL * TOUTT + (size_t)m * TOUTT + tcol] = s + bproj[m];
    else        out_gate[(size_t)b * TOUTT + tcol] = s + bgate[0];
  }
}

__global__ void __launch_bounds__(NTHR, 1)
decoder_loop(const int* __restrict__ tlen,
             const float* __restrict__ b_a, const float* __restrict__ b_d,
             const float* __restrict__ Wv,
             const float* __restrict__ bproj, const float* __restrict__ bgate,
             const f16* __restrict__ wta_h, const f16* __restrict__ wtd_h,
             const f16* __restrict__ pm16, const f16* __restrict__ enc16,
             const f16* __restrict__ pre_h,
             const f16* __restrict__ wqt, const f16* __restrict__ wpjt,
             const unsigned* __restrict__ wlocp, const unsigned* __restrict__ klp,
             f16* __restrict__ xa_h, f16* __restrict__ xd_h,
             float* __restrict__ ahf, float* __restrict__ dhf,
             float* __restrict__ ac, float* __restrict__ dc,
             float* __restrict__ ctxf, unsigned* bar,
             float* __restrict__ out_mel, float* __restrict__ out_gate,
             float* __restrict__ out_align) {
  __shared__ f16 wfA[28672];      // 57,344 B
  __shared__ f16 wfD[40960];      // 81,920 B
  __shared__ float smem[2048];    // 8,192 B  (Call/CallB | pl/red/ql/part)
  __shared__ unsigned awb[544];   // 2,176 B  f16x2 (aw, awc), +16 guard each side

  const int tid = threadIdx.x;
  const int bid = (int)blockIdx.x;
  const int lane = tid & 63;
  unsigned syncn = 0;

  // ---- prologue: pack B-fragments into LDS ----
  for (int i = tid; i < 3584; i += NTHR) {
    const int ks = i >> 6, l = i & 63;
    const int n = l & 15, kc = (l >> 4) * 8;
    const int gcol = (n >> 2) * 1024 + bid * 4 + (n & 3);
    const uint4 v = *reinterpret_cast<const uint4*>(wta_h + (size_t)gcol * KA + ks * 32 + kc);
    *reinterpret_cast<uint4*>(&wfA[(size_t)i * 8]) = v;
  }
  for (int i = tid; i < 5120; i += NTHR) {
    const int ks = i >> 6, l = i & 63;
    const int n = l & 15, kc = (l >> 4) * 8;
    const int gcol = (n >> 2) * 1024 + bid * 4 + (n & 3);
    const uint4 v = *reinterpret_cast<const uint4*>(wtd_h + (size_t)gcol * KD + ks * 32 + kc);
    *reinterpret_cast<uint4*>(&wfD[(size_t)i * 8]) = v;
  }
  for (int i = tid; i < 544; i += NTHR) awb[i] = 0u;
  // ---- zero global state ----
  {
    unsigned* za = (unsigned*)xa_h;   // xa+xd contiguous: 278,528 u32
    const int gid = bid * NTHR + tid;
    for (int i = gid; i < 278528; i += NBLK * NTHR) za[i] = 0u;
    float* zf = ahf;                  // ahf..ctxf contiguous: 393,216 f32
    for (int i = gid; i < 393216; i += NBLK * NTHR) zf[i] = 0.f;
  }
  gsync(bar, syncn);

  const int w = tid >> 6;
  const int mt = w & 3, kh = w >> 2;
  const int b = bid & 63;
  const int chn = bid >> 6;
  const int len = tlen[b];
  float awcf = 0.f;

  for (int t = 0; t <= TOUTT; ++t) {
    // ================= X: decoder LSTM (t-1), attention LSTM (t) =================
    if (t > 0) {
      const f16* xdP = xd_h + (size_t)((t - 1) & 1) * 163840;
      const f16* abase = xdP + (size_t)(kh * 40) * 2048 + mt * 512 + lane * 8;
      const f16* bbase = wfD + ((size_t)(kh * 40) * 64 + lane) * 8;
      f32x4 c = {0.f, 0.f, 0.f, 0.f};
      #pragma unroll 8
      for (int ks = 0; ks < 40; ++ks) {
        const f16x8 af = *reinterpret_cast<const f16x8*>(abase + (size_t)ks * 2048);
        const f16x8 bf = *reinterpret_cast<const f16x8*>(bbase + (size_t)ks * 512);
        c = __builtin_amdgcn_mfma_f32_16x16x32_f16(af, bf, c, 0, 0, 0);
      }
      lstm_tail(bid, tid, smem, c, kh, mt, lane, b_d, dc, dhf,
                xd_h + (size_t)(t & 1) * 163840, 1536, (f16*)0, 0);
    }
    if (t < TOUTT) {
      const f16* xaP = xa_h + (size_t)(t & 1) * 114688;
      const f16* preP = pre_h + (size_t)t * 16384;
      const f16* bbase = wfA + ((size_t)(kh * 28) * 64 + lane) * 8;
      f32x4 c = {0.f, 0.f, 0.f, 0.f};
      #pragma unroll 8
      for (int ks = 0; ks < 28; ++ks) {
        const int kg = kh * 28 + ks;
        const f16* ap = (kg < 8) ? preP : xaP;
        const f16x8 af = *reinterpret_cast<const f16x8*>(ap + (size_t)kg * 2048 + mt * 512 + lane * 8);
        const f16x8 bf = *reinterpret_cast<const f16x8*>(bbase + (size_t)ks * 512);
        c = __builtin_amdgcn_mfma_f32_16x16x32_f16(af, bf, c, 0, 0, 0);
      }
      lstm_tail(bid, tid, smem, c, kh, mt, lane, b_a, ac, ahf,
                xa_h + (size_t)((t + 1) & 1) * 114688, 768,
                xd_h + (size_t)(t & 1) * 163840, 0);
    }
    gsync(bar, syncn);

    // ================= Y: energies + softmax + ctx (+ melgate t-1) =================
    if (t < TOUTT) {
      // --- q partials -> qp(PART region), reduce -> ql ---
      {
        const int a = tid & 127, kq = tid >> 7;
        const f16* wr = wqt + (size_t)a * 1024 + kq * 256;
        const float* ar = ahf + (size_t)b * ALS + kq * 256;
        float s = 0.f;
        #pragma unroll 8
        for (int k8 = 0; k8 < 32; ++k8) {
          const f16x8 wv = *reinterpret_cast<const f16x8*>(wr + k8 * 8);
          #pragma unroll
          for (int j = 0; j < 8; ++j) s += ar[k8 * 8 + j] * (float)wv[j];
        }
        smem[PART_O + kq * 128 + a] = s;
      }
      __syncthreads();
      if (tid < 128) {
        const int a = tid;
        smem[QL_O + a + (a >> 5)] = smem[PART_O + a] + smem[PART_O + 128 + a] +
                                    smem[PART_O + 256 + a] + smem[PART_O + 384 + a];
      }
      __syncthreads();

      // --- conv (per-thread row tt=tid) ---
      const int tt = tid;
      float lf[32];
      #pragma unroll
      for (int f = 0; f < 32; ++f) lf[f] = 0.f;
      for (int k = 0; k < 31; ++k) {
        pk32 v; v.u = awb[tt + 1 + k];
        pk32 av; av.u = packh2((float)v.h[0], (float)v.h[1]);
        #pragma unroll
        for (int f = 0; f < 32; ++f) {
          pk32 kv; kv.u = klp[k * 32 + f];
          lf[f] = __builtin_amdgcn_fdot2(av.h, kv.h, lf[f], false);
        }
      }
      // pack lf -> f16x2 pairs
      pk32 l2[16];
      #pragma unroll
      for (int fp = 0; fp < 16; ++fp) l2[fp].u = packh2(lf[2 * fp], lf[2 * fp + 1]);

      // --- energies ---
      const f16* pmrow = pm16 + (size_t)(b * TIN + tt) * ATTD;
      float e = 0.f;
      #pragma unroll 2
      for (int ao = 0; ao < 16; ++ao) {
        const f16x8 pmv = *reinterpret_cast<const f16x8*>(pmrow + ao * 8);
        #pragma unroll
        for (int i = 0; i < 8; ++i) {
          const int a = ao * 8 + i;
          float pa = 0.f;
          #pragma unroll
          for (int fp = 0; fp < 16; ++fp) {
            pk32 wv; wv.u = wlocp[a * 16 + fp];
            pa = __builtin_amdgcn_fdot2(l2[fp].h, wv.h, pa, false);
          }
          e += Wv[a] * ftanh(smem[QL_O + a + (a >> 5)] + pa + (float)pmv[i]);
        }
      }

      // --- softmax over tt (512 threads) ---
      const float ee = (tt < len) ? e : -1e30f;
      float m = ee;
      #pragma unroll
      for (int o = 32; o > 0; o >>= 1) m = fmaxf(m, __shfl_xor(m, o));
      if (lane == 0) smem[RED_O + w] = m;
      __syncthreads();
      if (tid == 0) {
        float mm = smem[RED_O];
        #pragma unroll
        for (int i = 1; i < 8; ++i) mm = fmaxf(mm, smem[RED_O + i]);
        smem[RED_O + 8] = mm;
      }
      __syncthreads();
      const float M = smem[RED_O + 8];
      const float p = (tt < len) ? __expf(ee - M) : 0.f;
      float s = p;
      #pragma unroll
      for (int o = 32; o > 0; o >>= 1) s += __shfl_xor(s, o);
      if (lane == 0) smem[RED_O + w] = s;
      __syncthreads();
      if (tid == 0) {
        float ss = smem[RED_O];
        #pragma unroll
        for (int i = 1; i < 8; ++i) ss += smem[RED_O + i];
        smem[RED_O + 8] = ss;
      }
      __syncthreads();
      const float an = p * (1.f / smem[RED_O + 8]);
      smem[PL_O + tt] = an;
      awcf += an;
      awb[16 + tt] = packh2(an, awcf);
      if (chn == 0) out_align[((size_t)b * TOUTT + t) * TIN + tt] = an;
      __syncthreads();

      // --- ctx e-quarter (chn) ---
      {
        const int eo = lane & 15, sub4 = lane >> 4;
        float a8[8];
        #pragma unroll
        for (int i = 0; i < 8; ++i) a8[i] = 0.f;
        const f16* ebase = enc16 + (size_t)(b * TIN) * EEE + chn * 128 + eo * 8;
        #pragma unroll 4
        for (int j = 0; j < 16; ++j) {
          const int tj = w * 64 + sub4 * 16 + j;
          const float wv = smem[PL_O + tj];
          const f16x8 ev = *reinterpret_cast<const f16x8*>(ebase + (size_t)tj * EEE);
          #pragma unroll
          for (int i = 0; i < 8; ++i) a8[i] += wv * (float)ev[i];
        }
        #pragma unroll
        for (int i = 0; i < 8; ++i) {
          a8[i] += __shfl_xor(a8[i], 16);
          a8[i] += __shfl_xor(a8[i], 32);
        }
        if (lane < 16) {
          #pragma unroll
          for (int i = 0; i < 8; ++i) smem[PART_O + w * 128 + eo * 8 + i] = a8[i];
        }
      }
      __syncthreads();
      if (tid < 128) {
        float v = 0.f;
        #pragma unroll
        for (int ww = 0; ww < 8; ++ww) v += smem[PART_O + ww * 128 + tid];
        ctxf[(size_t)(t & 1) * (BB * EEE) + b * EEE + chn * 128 + tid] = v;
        smem[PL_O + tid] = v;   // pl dead now; stash for pairing
      }
      __syncthreads();
      if (tid < 64) {
        const int ecol = chn * 128 + 2 * tid;
        const unsigned pv = packh2(smem[PL_O + 2 * tid], smem[PL_O + 2 * tid + 1]);
        *reinterpret_cast<unsigned*>(xa_h + (size_t)((t + 1) & 1) * 114688 + fragaddr(b, 256 + ecol)) = pv;
        *reinterpret_cast<unsigned*>(xd_h + (size_t)(t & 1) * 163840 + fragaddr(b, 1024 + ecol)) = pv;
      }
    }
    if (t > 0 && chn >= 2) {
      __syncthreads();
      mel_gate2(b, chn - 2, t - 1, dhf, ctxf + (size_t)((t - 1) & 1) * (BB * EEE),
                wpjt, bproj, bgate, out_mel, out_gate, smem + PART_O);
    }
    if (t == TOUTT) break;
    gsync(bar, syncn);
  }
}

extern "C" void kernel_launch(void* const* d_in, const int* in_sizes, int n_in,
                              void* d_out, int out_size, void* d_ws, size_t ws_size,
                              hipStream_t stream) {
  (void)in_sizes; (void)n_in; (void)out_size; (void)ws_size;
  const float* enc    = (const float*)d_in[0];
  const float* dec_in = (const float*)d_in[1];
  const int*   tlen   = (const int*)d_in[2];
  const float* Wp1    = (const float*)d_in[3];
  const float* Wp2    = (const float*)d_in[4];
  const float* Wi_a   = (const float*)d_in[5];
  const float* Wh_a   = (const float*)d_in[6];
  const float* b_a    = (const float*)d_in[7];
  const float* Wq     = (const float*)d_in[8];
  const float* Wm     = (const float*)d_in[9];
  const float* Wv     = (const float*)d_in[10];
  const float* Kloc   = (const float*)d_in[11];
  const float* Wloc   = (const float*)d_in[12];
  const float* Wi_d   = (const float*)d_in[13];
  const float* Wh_d   = (const float*)d_in[14];
  const float* b_d    = (const float*)d_in[15];
  const float* Wproj  = (const float*)d_in[16];
  const float* bproj  = (const float*)d_in[17];
  const float* Wgate  = (const float*)d_in[18];
  const float* bgate  = (const float*)d_in[19];

  float* ws = (float*)d_ws;
  f16*   wta_h = (f16*)(ws + WTA_OFF);
  f16*   wtd_h = (f16*)(ws + WTD_OFF);
  f16*   pm16  = (f16*)(ws + PM16_OFF);
  f16*   e16   = (f16*)(ws + ENC16_OFF);
  f16*   pre_h = (f16*)(ws + PRE_OFF);
  f16*   xa_h  = (f16*)(ws + XA_OFF);
  f16*   xd_h  = (f16*)(ws + XD_OFF);
  float* ahf   = ws + AHF_OFF;
  float* dhf   = ws + DHF_OFF;
  float* ac    = ws + AC_OFF;
  float* dc    = ws + DC_OFF;
  float* ctxf  = ws + CTXF_OFF;
  f16*   wqt   = (f16*)(ws + WQT_OFF);
  f16*   wpjt  = (f16*)(ws + WPJT_OFF);
  f16*   wp1t  = (f16*)(ws + WP1T_OFF);
  f16*   wp2t  = (f16*)(ws + WP2T_OFF);
  unsigned* wlocp = (unsigned*)(ws + WLP_OFF);
  unsigned* klp   = (unsigned*)(ws + KLP_OFF);
  unsigned* bar   = (unsigned*)(ws + BAR_OFF);

  float* out_mel   = (float*)d_out;
  float* out_gate  = out_mel + (size_t)BB * NMEL * TOUTT;
  float* out_align = out_gate + (size_t)BB * TOUTT;

  hipMemsetAsync(bar, 0, 272 * sizeof(unsigned), stream);
  transA<<<dim3(28 * 64), dim3(256), 0, stream>>>(Wi_a, Wh_a, wta_h);
  transD<<<dim3(40 * 64), dim3(256), 0, stream>>>(Wi_d, Wh_d, wtd_h);
  pmk<<<dim3(BB * TIN), dim3(128), 0, stream>>>(enc, Wm, pm16);
  enc16k<<<dim3(4096), dim3(512), 0, stream>>>(enc, e16);
  transAux<<<dim3(673), dim3(512), 0, stream>>>(Wq, Wproj, Wgate, Wp1, Wp2, Wloc, Kloc,
                                                wqt, wpjt, wp1t, wp2t, wlocp, klp);
  prenetk<<<dim3(TOUTT), dim3(512), 0, stream>>>(dec_in, wp1t, wp2t, pre_h);
  decoder_loop<<<dim3(NBLK), dim3(NTHR), 0, stream>>>(
      tlen, b_a, b_d, Wv, bproj, bgate,
      wta_h, wtd_h, pm16, e16, pre_h, wqt, wpjt, wlocp, klp,
      xa_h, xd_h, ahf, dhf, ac, dc, ctxf, bar,
      out_mel, out_gate, out_align);
}